// Round 1
// baseline (4470.380 us; speedup 1.0000x reference)
//
#include <hip/hip_runtime.h>

#define N_LIG 16384
#define M_POC 32768
#define N_TOT (N_LIG + M_POC)          // 49152
#define E_LIG 163840
#define E_POC 327680
#define E_CROSS (N_LIG * 8)            // 131072
#define E_TOT (E_LIG + E_POC + E_CROSS) // 622592
#define TE 16                           // edges (or nodes) per wave tile

__device__ __forceinline__ float silu_f(float v) {
    return v / (1.0f + __expf(-v));
}

__device__ __forceinline__ float tanh_f(float v) {
    float a = fabsf(v);
    float t = __expf(-2.0f * a);
    float r = (1.0f - t) / (1.0f + t);
    return copysignf(r, v);
}

// ---------------- setup kernels ----------------

__global__ void k_build_edges(const int* __restrict__ lig_ei, const int* __restrict__ poc_ei,
                              const int* __restrict__ cross_ei,
                              int* __restrict__ srcA, int* __restrict__ dstA) {
    int e = blockIdx.x * blockDim.x + threadIdx.x;
    if (e >= E_TOT) return;
    int s, d;
    if (e < E_LIG) {
        s = lig_ei[e];
        d = lig_ei[E_LIG + e];
    } else if (e < E_LIG + E_POC) {
        int i = e - E_LIG;
        s = poc_ei[i] + N_LIG;
        d = poc_ei[E_POC + i] + N_LIG;
    } else {
        int i = e - E_LIG - E_POC;
        s = cross_ei[i] + N_LIG;   // src in pocket
        d = cross_ei[E_CROSS + i]; // dst in ligand
    }
    srcA[e] = s;
    dstA[e] = d;
}

// Pack per-layer weights into k-chunked layout: chunk c holds k = c*4..c*4+3,
// stored as [c][j(0..63)][kk(0..3)] so one float4/lane load feeds 4 FMAs.
// Regions (in 256-float chunks) per layer: W1(49) W2(16) Wx1(16) Wh1(32) Wh2(16) = 129
__global__ void k_pack_weights(const float* __restrict__ phi_e_W1,
                               const float* __restrict__ phi_e_W2,
                               const float* __restrict__ phi_x_W1,
                               const float* __restrict__ phi_h_W1,
                               const float* __restrict__ phi_h_W2,
                               float* __restrict__ Wp) {
    int idx = blockIdx.x * blockDim.x + threadIdx.x;
    if (idx >= 4 * 129 * 256) return;
    int l = idx / (129 * 256);
    int rem = idx - l * 129 * 256;
    int c = rem / 256;
    int q = rem - c * 256;
    int j = q >> 2;
    int kk = q & 3;
    const float* W; int Ksrc; int k4;
    if (c < 49)       { W = phi_e_W1 + l * 193 * 64; Ksrc = 193; k4 = c; }
    else if (c < 65)  { W = phi_e_W2 + l * 64 * 64;  Ksrc = 64;  k4 = c - 49; }
    else if (c < 81)  { W = phi_x_W1 + l * 64 * 64;  Ksrc = 64;  k4 = c - 65; }
    else if (c < 113) { W = phi_h_W1 + l * 128 * 64; Ksrc = 128; k4 = c - 81; }
    else              { W = phi_h_W2 + l * 64 * 64;  Ksrc = 64;  k4 = c - 113; }
    int k = k4 * 4 + kk;
    Wp[idx] = (k < Ksrc) ? W[k * 64 + j] : 0.0f;
}

__global__ void k_embed(const float* __restrict__ lig_x, const float* __restrict__ lig_h,
                        const float* __restrict__ poc_x, const float* __restrict__ poc_h,
                        const float* __restrict__ t,
                        const float* __restrict__ ligW, const float* __restrict__ ligB,
                        const float* __restrict__ pocW, const float* __restrict__ pocB,
                        float* __restrict__ h, float* __restrict__ x) {
    int gid = blockIdx.x * blockDim.x + threadIdx.x;
    int n = gid >> 6;
    int lane = gid & 63;
    if (n >= N_TOT) return;
    if (n < N_LIG) {
        float a = ligB[lane];
        #pragma unroll
        for (int k = 0; k < 17; ++k) a = fmaf(lig_h[n * 17 + k], ligW[k * 64 + lane], a);
        a = fmaf(t[0], ligW[17 * 64 + lane], a);
        h[n * 64 + lane] = a;
        if (lane < 3) x[n * 3 + lane] = lig_x[n * 3 + lane];
    } else {
        int p = n - N_LIG;
        float a = pocB[lane];
        #pragma unroll
        for (int k = 0; k < 29; ++k) a = fmaf(poc_h[p * 29 + k], pocW[k * 64 + lane], a);
        h[n * 64 + lane] = a;
        if (lane < 3) x[n * 3 + lane] = poc_x[p * 3 + lane];
    }
}

// ---------------- per-layer edge kernel ----------------
// Block = 256 (4 waves). Wave handles TE=16 consecutive edges.
// Per-wave LDS region: e_in[16][196] (rows padded to 196 for float4 + k-pad),
// m written back over e_in head (16x64), diff[16][4] at tail.
#define WAVE_LDS (TE * 196 + TE * 4)   // 3200 floats = 12.8 KB/wave, 51.2 KB/block

__global__ __launch_bounds__(256) void k_edge(
    const float* __restrict__ h, const float* __restrict__ x,
    const int* __restrict__ srcA, const int* __restrict__ dstA,
    const float* __restrict__ lig_attr, const float* __restrict__ poc_attr,
    const float* __restrict__ cross_attr,
    const float* __restrict__ ligW, const float* __restrict__ ligB,
    const float* __restrict__ pocW, const float* __restrict__ pocB,
    const float* __restrict__ crossW, const float* __restrict__ crossB,
    const float* __restrict__ W1p, const float* __restrict__ b1,
    const float* __restrict__ W2p, const float* __restrict__ b2,
    const float* __restrict__ Wx1p, const float* __restrict__ bx1,
    const float* __restrict__ Wx2, const float* __restrict__ bx2,
    float* __restrict__ msg_agg, float* __restrict__ coord_agg) {
    __shared__ __align__(16) float lds[4][WAVE_LDS];
    const int lane = threadIdx.x & 63;
    const int wave = threadIdx.x >> 6;
    float* einL = lds[wave];
    float* dfL = einL + TE * 196;
    const int base = (blockIdx.x * 4 + wave) * TE;

    // ---- stage e_in = [h_src(64) | h_dst(64) | dist(1) | eattr(64) | pad(3)] ----
    for (int r = 0; r < TE; ++r) {
        const int e = base + r;
        const int s = srcA[e], d = dstA[e];
        einL[r * 196 + lane] = h[s * 64 + lane];
        einL[r * 196 + 64 + lane] = h[d * 64 + lane];
        float d0 = x[s * 3 + 0] - x[d * 3 + 0];
        float d1 = x[s * 3 + 1] - x[d * 3 + 1];
        float d2 = x[s * 3 + 2] - x[d * 3 + 2];
        float dist = (d0 * d0 + d1 * d1 + d2 * d2) * 0.01f;
        if (lane == 0) einL[r * 196 + 128] = dist;
        if (lane < 3) dfL[r * 4 + lane] = (lane == 0) ? d0 : ((lane == 1) ? d1 : d2);
        // eattr = raw_attr @ ee_W + ee_b (recomputed per layer; cheap)
        const float* W; const float* B; const float* attr; int K;
        if (e < E_LIG) { W = ligW; B = ligB; attr = lig_attr + (size_t)e * 6; K = 6; }
        else if (e < E_LIG + E_POC) { W = pocW; B = pocB; attr = poc_attr + (size_t)(e - E_LIG) * 16; K = 16; }
        else { W = crossW; B = crossB; attr = cross_attr + (size_t)(e - E_LIG - E_POC) * 16; K = 16; }
        float ea = B[lane];
        for (int k = 0; k < K; ++k) ea = fmaf(attr[k], W[k * 64 + lane], ea);
        einL[r * 196 + 129 + lane] = ea;
        if (lane < 3) einL[r * 196 + 193 + lane] = 0.0f;
    }
    __syncthreads();

    // ---- GEMM1: m1 = silu(e_in @ W1 + b1), acc over 49 k-chunks ----
    float acc[TE];
    #pragma unroll
    for (int r = 0; r < TE; ++r) acc[r] = b1[lane];
    for (int c = 0; c < 49; ++c) {
        const float4 w = *(const float4*)(W1p + (c * 64 + lane) * 4);
        #pragma unroll
        for (int r = 0; r < TE; ++r) {
            const float4 ev = *(const float4*)(einL + r * 196 + c * 4);
            acc[r] = fmaf(ev.x, w.x, fmaf(ev.y, w.y, fmaf(ev.z, w.z, fmaf(ev.w, w.w, acc[r]))));
        }
    }
    __syncthreads();
    // write m1 over the (now dead) head of e_in region: rows of 64
    #pragma unroll
    for (int r = 0; r < TE; ++r) einL[r * 64 + lane] = silu_f(acc[r]);
    __syncthreads();

    // ---- GEMM2: m = silu(m1 @ W2 + b2) ----
    float acc2[TE];
    #pragma unroll
    for (int r = 0; r < TE; ++r) acc2[r] = b2[lane];
    for (int c = 0; c < 16; ++c) {
        const float4 w = *(const float4*)(W2p + (c * 64 + lane) * 4);
        #pragma unroll
        for (int r = 0; r < TE; ++r) {
            const float4 mv = *(const float4*)(einL + r * 64 + c * 4);
            acc2[r] = fmaf(mv.x, w.x, fmaf(mv.y, w.y, fmaf(mv.z, w.z, fmaf(mv.w, w.w, acc2[r]))));
        }
    }
    float m[TE];
    #pragma unroll
    for (int r = 0; r < TE; ++r) m[r] = silu_f(acc2[r]);
    __syncthreads();
    #pragma unroll
    for (int r = 0; r < TE; ++r) einL[r * 64 + lane] = m[r];
    __syncthreads();

    // ---- GEMM3: p = silu(m @ Wx1 + bx1) ----
    float acc3[TE];
    #pragma unroll
    for (int r = 0; r < TE; ++r) acc3[r] = bx1[lane];
    for (int c = 0; c < 16; ++c) {
        const float4 w = *(const float4*)(Wx1p + (c * 64 + lane) * 4);
        #pragma unroll
        for (int r = 0; r < TE; ++r) {
            const float4 mv = *(const float4*)(einL + r * 64 + c * 4);
            acc3[r] = fmaf(mv.x, w.x, fmaf(mv.y, w.y, fmaf(mv.z, w.z, fmaf(mv.w, w.w, acc3[r]))));
        }
    }

    // ---- cw = tanh(p @ Wx2 + bx2); atomic aggregation ----
    const float wx2v = Wx2[lane];
    const float bx2v = bx2[0];
    for (int r = 0; r < TE; ++r) {
        float p = silu_f(acc3[r]) * wx2v;
        #pragma unroll
        for (int off = 32; off > 0; off >>= 1) p += __shfl_xor(p, off, 64);
        const float cw = tanh_f(p + bx2v);
        const int e = base + r;
        const int d = dstA[e];
        atomicAdd(&msg_agg[d * 64 + lane], m[r]);
        if (d < N_LIG && lane < 3)
            atomicAdd(&coord_agg[d * 3 + lane], dfL[r * 4 + lane] * cw);
    }
}

// ---------------- per-layer node update ----------------
__global__ __launch_bounds__(256) void k_node(
    float* __restrict__ h, float* __restrict__ x,
    const float* __restrict__ msg, const float* __restrict__ coord,
    const float* __restrict__ Wh1p, const float* __restrict__ bh1,
    const float* __restrict__ Wh2p, const float* __restrict__ bh2) {
    __shared__ __align__(16) float lds[4][TE * 128];
    const int lane = threadIdx.x & 63;
    const int wave = threadIdx.x >> 6;
    float* inL = lds[wave];
    const int base = (blockIdx.x * 4 + wave) * TE;

    for (int r = 0; r < TE; ++r) {
        const int n = base + r;
        inL[r * 128 + lane] = h[n * 64 + lane];
        inL[r * 128 + 64 + lane] = msg[n * 64 + lane];
    }
    __syncthreads();

    float acc[TE];
    #pragma unroll
    for (int r = 0; r < TE; ++r) acc[r] = bh1[lane];
    for (int c = 0; c < 32; ++c) {
        const float4 w = *(const float4*)(Wh1p + (c * 64 + lane) * 4);
        #pragma unroll
        for (int r = 0; r < TE; ++r) {
            const float4 v = *(const float4*)(inL + r * 128 + c * 4);
            acc[r] = fmaf(v.x, w.x, fmaf(v.y, w.y, fmaf(v.z, w.z, fmaf(v.w, w.w, acc[r]))));
        }
    }
    __syncthreads();
    #pragma unroll
    for (int r = 0; r < TE; ++r) inL[r * 64 + lane] = silu_f(acc[r]);
    __syncthreads();

    float acc2[TE];
    #pragma unroll
    for (int r = 0; r < TE; ++r) acc2[r] = bh2[lane];
    for (int c = 0; c < 16; ++c) {
        const float4 w = *(const float4*)(Wh2p + (c * 64 + lane) * 4);
        #pragma unroll
        for (int r = 0; r < TE; ++r) {
            const float4 v = *(const float4*)(inL + r * 64 + c * 4);
            acc2[r] = fmaf(v.x, w.x, fmaf(v.y, w.y, fmaf(v.z, w.z, fmaf(v.w, w.w, acc2[r]))));
        }
    }
    for (int r = 0; r < TE; ++r) {
        const int n = base + r;
        h[n * 64 + lane] += acc2[r];
        if (lane < 3 && n < N_LIG) x[n * 3 + lane] += coord[n * 3 + lane];
    }
}

// ---------------- output head ----------------
__global__ void k_out(const float* __restrict__ h, const float* __restrict__ x,
                      const float* __restrict__ lig_x,
                      const float* __restrict__ oW1, const float* __restrict__ ob1,
                      const float* __restrict__ oW2, const float* __restrict__ ob2,
                      float* __restrict__ out) {
    int gid = blockIdx.x * blockDim.x + threadIdx.x;
    int n = gid >> 6;
    int lane = gid & 63;
    if (n >= N_LIG) return;
    float hv = h[n * 64 + lane];
    float a = ob1[lane];
    #pragma unroll
    for (int k = 0; k < 64; ++k) a = fmaf(__shfl(hv, k, 64), oW1[k * 64 + lane], a);
    float p = silu_f(a) * oW2[lane];
    #pragma unroll
    for (int off = 32; off > 0; off >>= 1) p += __shfl_xor(p, off, 64);
    float scale = p + ob2[0];
    if (lane < 3) out[n * 3 + lane] = scale * (x[n * 3 + lane] - lig_x[n * 3 + lane]);
}

// ---------------- launch ----------------
extern "C" void kernel_launch(void* const* d_in, const int* in_sizes, int n_in,
                              void* d_out, int out_size, void* d_ws, size_t ws_size,
                              hipStream_t stream) {
    const float* lig_x      = (const float*)d_in[0];
    const float* lig_h      = (const float*)d_in[1];
    const float* poc_x      = (const float*)d_in[2];
    const float* poc_h      = (const float*)d_in[3];
    const int*   lig_ei     = (const int*)d_in[4];
    const float* lig_attr   = (const float*)d_in[5];
    const int*   poc_ei     = (const int*)d_in[6];
    const float* poc_attr   = (const float*)d_in[7];
    const int*   cross_ei   = (const int*)d_in[8];
    const float* cross_attr = (const float*)d_in[9];
    const float* t          = (const float*)d_in[10];
    const float* lig_emb_W  = (const float*)d_in[11];
    const float* lig_emb_b  = (const float*)d_in[12];
    const float* poc_emb_W  = (const float*)d_in[13];
    const float* poc_emb_b  = (const float*)d_in[14];
    const float* lig_ee_W   = (const float*)d_in[15];
    const float* lig_ee_b   = (const float*)d_in[16];
    const float* poc_ee_W   = (const float*)d_in[17];
    const float* poc_ee_b   = (const float*)d_in[18];
    const float* cross_ee_W = (const float*)d_in[19];
    const float* cross_ee_b = (const float*)d_in[20];
    const float* phi_e_W1   = (const float*)d_in[21];
    const float* phi_e_b1   = (const float*)d_in[22];
    const float* phi_e_W2   = (const float*)d_in[23];
    const float* phi_e_b2   = (const float*)d_in[24];
    const float* phi_x_W1   = (const float*)d_in[25];
    const float* phi_x_b1   = (const float*)d_in[26];
    const float* phi_x_W2   = (const float*)d_in[27];
    const float* phi_x_b2   = (const float*)d_in[28];
    const float* phi_h_W1   = (const float*)d_in[29];
    const float* phi_h_b1   = (const float*)d_in[30];
    const float* phi_h_W2   = (const float*)d_in[31];
    const float* phi_h_b2   = (const float*)d_in[32];
    const float* out_W1     = (const float*)d_in[33];
    const float* out_b1     = (const float*)d_in[34];
    const float* out_W2     = (const float*)d_in[35];
    const float* out_b2     = (const float*)d_in[36];

    // workspace layout (floats): h | msg | x | coord | Wp | srcA | dstA  (~32 MB)
    float* h     = (float*)d_ws;
    float* msg   = h + (size_t)N_TOT * 64;
    float* xx    = msg + (size_t)N_TOT * 64;
    float* coord = xx + (size_t)N_TOT * 3;
    float* Wp    = coord + (size_t)N_TOT * 3;
    int*   srcA  = (int*)(Wp + 4 * 129 * 256);
    int*   dstA  = srcA + E_TOT;

    k_build_edges<<<E_TOT / 256, 256, 0, stream>>>(lig_ei, poc_ei, cross_ei, srcA, dstA);
    k_pack_weights<<<(4 * 129 * 256) / 256, 256, 0, stream>>>(
        phi_e_W1, phi_e_W2, phi_x_W1, phi_h_W1, phi_h_W2, Wp);
    k_embed<<<(N_TOT * 64) / 256, 256, 0, stream>>>(
        lig_x, lig_h, poc_x, poc_h, t, lig_emb_W, lig_emb_b, poc_emb_W, poc_emb_b, h, xx);

    for (int l = 0; l < 4; ++l) {
        hipMemsetAsync(msg, 0, (size_t)N_TOT * 64 * sizeof(float), stream);
        hipMemsetAsync(coord, 0, (size_t)N_TOT * 3 * sizeof(float), stream);
        const float* Wl = Wp + (size_t)l * 129 * 256;
        k_edge<<<E_TOT / 64, 256, 0, stream>>>(
            h, xx, srcA, dstA, lig_attr, poc_attr, cross_attr,
            lig_ee_W, lig_ee_b, poc_ee_W, poc_ee_b, cross_ee_W, cross_ee_b,
            Wl, phi_e_b1 + l * 64,
            Wl + 49 * 256, phi_e_b2 + l * 64,
            Wl + 65 * 256, phi_x_b1 + l * 64,
            phi_x_W2 + l * 64, phi_x_b2 + l,
            msg, coord);
        k_node<<<N_TOT / 64, 256, 0, stream>>>(
            h, xx, msg, coord,
            Wl + 81 * 256, phi_h_b1 + l * 64,
            Wl + 113 * 256, phi_h_b2 + l * 64);
    }

    k_out<<<(N_LIG * 64) / 256, 256, 0, stream>>>(
        h, xx, lig_x, out_W1, out_b1, out_W2, out_b2, (float*)d_out);
}

// Round 2
// 2540.231 us; speedup vs baseline: 1.7598x; 1.7598x over previous
//
#include <hip/hip_runtime.h>

#define N_LIG 16384
#define M_POC 32768
#define N_TOT (N_LIG + M_POC)          // 49152
#define E_LIG 163840
#define E_POC 327680
#define E_CROSS (N_LIG * 8)            // 131072
#define E_TOT (E_LIG + E_POC + E_CROSS) // 622592
#define TE 16                           // edges/nodes per wave tile

typedef __bf16 bf16_t;
typedef bf16_t bf16x8 __attribute__((ext_vector_type(8)));
typedef float f32x4 __attribute__((ext_vector_type(4)));

// LDS row strides (bf16 elements) chosen so 16-row b128 A-frag reads are <=2-way bank aliased
#define S1 232   // e_in rows: 193 data -> pad 224 (7 k-chunks of 32) -> 232 for banks
#define S2 72    // m rows: 64 data -> 72
// per-wave LDS bytes: einA 16*232*2=7424 | mA 16*72*2=2304 | dfL 16*4*4=256 | dstL 16*4=64
#define WAVE_BYTES (7424 + 2304 + 256 + 64)   // 10048 -> 40192/block -> 4 blocks/CU

__device__ __forceinline__ float silu_f(float v) {
    return v / (1.0f + __expf(-v));
}

__device__ __forceinline__ float tanh_f(float v) {
    float a = fabsf(v);
    float t = __expf(-2.0f * a);
    float r = (1.0f - t) / (1.0f + t);
    return copysignf(r, v);
}

// ---------------- setup kernels ----------------

__global__ void k_build_edges(const int* __restrict__ lig_ei, const int* __restrict__ poc_ei,
                              const int* __restrict__ cross_ei,
                              int* __restrict__ srcA, int* __restrict__ dstA) {
    int e = blockIdx.x * blockDim.x + threadIdx.x;
    if (e >= E_TOT) return;
    int s, d;
    if (e < E_LIG) {
        s = lig_ei[e];
        d = lig_ei[E_LIG + e];
    } else if (e < E_LIG + E_POC) {
        int i = e - E_LIG;
        s = poc_ei[i] + N_LIG;
        d = poc_ei[E_POC + i] + N_LIG;
    } else {
        int i = e - E_LIG - E_POC;
        s = cross_ei[i] + N_LIG;
        d = cross_ei[E_CROSS + i];
    }
    srcA[e] = s;
    dstA[e] = d;
}

// f32 k-chunked pack for the (still-VALU) node kernel: Wh1(32 chunks) Wh2(16) per layer
__global__ void k_pack_weights(const float* __restrict__ phi_h_W1,
                               const float* __restrict__ phi_h_W2,
                               float* __restrict__ Wp) {
    int idx = blockIdx.x * blockDim.x + threadIdx.x;
    if (idx >= 4 * 48 * 256) return;
    int l = idx / (48 * 256);
    int rem = idx - l * 48 * 256;
    int c = rem / 256;
    int q = rem - c * 256;
    int j = q >> 2;
    int kk = q & 3;
    const float* W; int Ksrc; int k4;
    if (c < 32) { W = phi_h_W1 + l * 128 * 64; Ksrc = 128; k4 = c; }
    else        { W = phi_h_W2 + l * 64 * 64;  Ksrc = 64;  k4 = c - 32; }
    int k = k4 * 4 + kk;
    Wp[idx] = (k < Ksrc) ? W[k * 64 + j] : 0.0f;
}

// bf16 MFMA B-fragment pack for edge GEMMs.
// Per layer: 11 k-chunk-groups x 4 n-tiles x 64 lanes x 8 j.
//   cg 0..6  : phi_e_W1 [193x64], kbase = cg*32
//   cg 7..8  : phi_e_W2 [64x64],  kbase = (cg-7)*32
//   cg 9..10 : phi_x_W1 [64x64],  kbase = (cg-9)*32
// Fragment element: lane L, j -> B[k = kbase + (L>>4)*8 + j][n = nt*16 + (L&15)]
#define BG_PER_LAYER (11 * 4 * 64 * 8)   // 22528 bf16
__global__ void k_pack_wb(const float* __restrict__ phi_e_W1,
                          const float* __restrict__ phi_e_W2,
                          const float* __restrict__ phi_x_W1,
                          bf16_t* __restrict__ Bg) {
    int tid = blockIdx.x * blockDim.x + threadIdx.x;
    if (tid >= 4 * 11 * 4 * 64) return;
    int l = tid / (11 * 4 * 64);
    int rem = tid - l * (11 * 4 * 64);
    int cg = rem / (4 * 64);
    int rem2 = rem - cg * (4 * 64);
    int nt = rem2 >> 6;
    int lane = rem2 & 63;
    const float* W; int K; int kb;
    if (cg < 7)      { W = phi_e_W1 + l * 193 * 64; K = 193; kb = cg * 32; }
    else if (cg < 9) { W = phi_e_W2 + l * 64 * 64;  K = 64;  kb = (cg - 7) * 32; }
    else             { W = phi_x_W1 + l * 64 * 64;  K = 64;  kb = (cg - 9) * 32; }
    int col = nt * 16 + (lane & 15);
    int k0 = kb + (lane >> 4) * 8;
    #pragma unroll
    for (int j = 0; j < 8; ++j) {
        int k = k0 + j;
        Bg[(size_t)tid * 8 + j] = (bf16_t)((k < K) ? W[k * 64 + col] : 0.0f);
    }
}

__global__ void k_embed(const float* __restrict__ lig_x, const float* __restrict__ lig_h,
                        const float* __restrict__ poc_x, const float* __restrict__ poc_h,
                        const float* __restrict__ t,
                        const float* __restrict__ ligW, const float* __restrict__ ligB,
                        const float* __restrict__ pocW, const float* __restrict__ pocB,
                        float* __restrict__ h, float* __restrict__ x) {
    int gid = blockIdx.x * blockDim.x + threadIdx.x;
    int n = gid >> 6;
    int lane = gid & 63;
    if (n >= N_TOT) return;
    if (n < N_LIG) {
        float a = ligB[lane];
        #pragma unroll
        for (int k = 0; k < 17; ++k) a = fmaf(lig_h[n * 17 + k], ligW[k * 64 + lane], a);
        a = fmaf(t[0], ligW[17 * 64 + lane], a);
        h[n * 64 + lane] = a;
        if (lane < 3) x[n * 3 + lane] = lig_x[n * 3 + lane];
    } else {
        int p = n - N_LIG;
        float a = pocB[lane];
        #pragma unroll
        for (int k = 0; k < 29; ++k) a = fmaf(poc_h[p * 29 + k], pocW[k * 64 + lane], a);
        h[n * 64 + lane] = a;
        if (lane < 3) x[n * 3 + lane] = poc_x[p * 3 + lane];
    }
}

// ---------------- per-layer MFMA edge kernel ----------------
// Block = 256 (4 waves); wave = 16 edges. 3 GEMMs via mfma_f32_16x16x32_bf16.
// A-frag: A[m=lane&15][k=(lane>>4)*8+j] from LDS; B-frag prepacked in global (cache-hot);
// C/D: col=lane&15, row=(lane>>4)*4+reg. h stays f32 globally; bf16 only as MFMA input.
__global__ __launch_bounds__(256, 4) void k_edge_mfma(
    const float* __restrict__ hG, const float* __restrict__ x,
    const int* __restrict__ srcA, const int* __restrict__ dstA,
    const float* __restrict__ lig_attr, const float* __restrict__ poc_attr,
    const float* __restrict__ cross_attr,
    const float* __restrict__ ligW, const float* __restrict__ ligB,
    const float* __restrict__ pocW, const float* __restrict__ pocB,
    const float* __restrict__ crossW, const float* __restrict__ crossB,
    const bf16_t* __restrict__ Bg,     // this layer's fragment pack
    const float* __restrict__ b1, const float* __restrict__ b2,
    const float* __restrict__ bx1,
    const float* __restrict__ Wx2, const float* __restrict__ bx2,
    float* __restrict__ msg_agg, float* __restrict__ coord_agg) {
    __shared__ __align__(16) char lds[4 * WAVE_BYTES];
    const int lane = threadIdx.x & 63;
    const int wave = threadIdx.x >> 6;
    bf16_t* einA = (bf16_t*)(lds + wave * WAVE_BYTES);
    bf16_t* mA   = (bf16_t*)(lds + wave * WAVE_BYTES + 7424);
    float*  dfL  = (float*)(lds + wave * WAVE_BYTES + 7424 + 2304);
    int*    dstL = (int*)(lds + wave * WAVE_BYTES + 7424 + 2304 + 256);
    const int base = (blockIdx.x * 4 + wave) * TE;

    // edge type is uniform across the 16-edge tile (region sizes are multiples of 16)
    const float* eW; const float* eB; const float* attrBase; int K; int astride;
    if (base < E_LIG) { eW = ligW; eB = ligB; attrBase = lig_attr + (size_t)base * 6; K = 6; astride = 6; }
    else if (base < E_LIG + E_POC) { eW = pocW; eB = pocB; attrBase = poc_attr + (size_t)(base - E_LIG) * 16; K = 16; astride = 16; }
    else { eW = crossW; eB = crossB; attrBase = cross_attr + (size_t)(base - E_LIG - E_POC) * 16; K = 16; astride = 16; }
    // hoist this lane's edge-embedding weight column (loaded once per tile, not per row)
    float wcol[16];
    #pragma unroll
    for (int k = 0; k < 16; ++k) wcol[k] = (k < K) ? eW[k * 64 + lane] : 0.0f;
    const float ebv = eB[lane];

    // ---- stage e_in rows: [h_src(64) | h_dst(64) | dist | eattr(64) | 0-pad to 224] ----
    for (int r = 0; r < TE; ++r) {
        const int e = base + r;
        const int s = srcA[e], d = dstA[e];
        bf16_t* row = einA + r * S1;
        row[lane] = (bf16_t)hG[s * 64 + lane];
        row[64 + lane] = (bf16_t)hG[d * 64 + lane];
        float d0 = x[s * 3 + 0] - x[d * 3 + 0];
        float d1 = x[s * 3 + 1] - x[d * 3 + 1];
        float d2 = x[s * 3 + 2] - x[d * 3 + 2];
        float dist = (d0 * d0 + d1 * d1 + d2 * d2) * 0.01f;
        if (lane == 0) { row[128] = (bf16_t)dist; dstL[r] = d; }
        if (lane < 3) dfL[r * 4 + lane] = (lane == 0) ? d0 : ((lane == 1) ? d1 : d2);
        const float* attr = attrBase + r * astride;
        float ea = ebv;
        for (int k = 0; k < K; ++k) ea = fmaf(attr[k], wcol[k], ea);
        row[129 + lane] = (bf16_t)ea;
        if (lane < 31) row[193 + lane] = (bf16_t)0.0f;
    }
    __syncthreads();

    const int mcol = lane & 15;
    const int mrow0 = (lane >> 4) * 4;

    // ---- GEMM1: m1 = silu(e_in @ W1 + b1) : 7 k-chunks x 4 n-tiles ----
    f32x4 acc1[4];
    #pragma unroll
    for (int nt = 0; nt < 4; ++nt) {
        float bv = b1[nt * 16 + mcol];
        acc1[nt] = (f32x4){bv, bv, bv, bv};
    }
    const bf16_t* aBase = einA + mcol * S1 + (lane >> 4) * 8;
    #pragma unroll
    for (int c = 0; c < 7; ++c) {
        bf16x8 af = *(const bf16x8*)(aBase + c * 32);
        #pragma unroll
        for (int nt = 0; nt < 4; ++nt) {
            bf16x8 bfr = *(const bf16x8*)(Bg + ((size_t)(c * 4 + nt) * 64 + lane) * 8);
            acc1[nt] = __builtin_amdgcn_mfma_f32_16x16x32_bf16(af, bfr, acc1[nt], 0, 0, 0);
        }
    }
    __syncthreads();
    #pragma unroll
    for (int nt = 0; nt < 4; ++nt)
        #pragma unroll
        for (int g = 0; g < 4; ++g)
            mA[(mrow0 + g) * S2 + nt * 16 + mcol] = (bf16_t)silu_f(acc1[nt][g]);
    __syncthreads();

    // ---- GEMM2: m = silu(m1 @ W2 + b2) : 2 k-chunks x 4 n-tiles ----
    f32x4 acc2[4];
    #pragma unroll
    for (int nt = 0; nt < 4; ++nt) {
        float bv = b2[nt * 16 + mcol];
        acc2[nt] = (f32x4){bv, bv, bv, bv};
    }
    const bf16_t* aBase2 = mA + mcol * S2 + (lane >> 4) * 8;
    const bf16_t* Bg2 = Bg + 7 * 4 * 64 * 8;
    #pragma unroll
    for (int c = 0; c < 2; ++c) {
        bf16x8 af = *(const bf16x8*)(aBase2 + c * 32);
        #pragma unroll
        for (int nt = 0; nt < 4; ++nt) {
            bf16x8 bfr = *(const bf16x8*)(Bg2 + ((size_t)(c * 4 + nt) * 64 + lane) * 8);
            acc2[nt] = __builtin_amdgcn_mfma_f32_16x16x32_bf16(af, bfr, acc2[nt], 0, 0, 0);
        }
    }
    float mv[4][4];
    #pragma unroll
    for (int nt = 0; nt < 4; ++nt)
        #pragma unroll
        for (int g = 0; g < 4; ++g)
            mv[nt][g] = silu_f(acc2[nt][g]);
    __syncthreads();
    #pragma unroll
    for (int nt = 0; nt < 4; ++nt)
        #pragma unroll
        for (int g = 0; g < 4; ++g)
            mA[(mrow0 + g) * S2 + nt * 16 + mcol] = (bf16_t)mv[nt][g];
    __syncthreads();

    // dst node per C-row (from LDS), then f32 atomic msg aggregation
    int dg[4];
    #pragma unroll
    for (int g = 0; g < 4; ++g) dg[g] = dstL[mrow0 + g];
    #pragma unroll
    for (int nt = 0; nt < 4; ++nt)
        #pragma unroll
        for (int g = 0; g < 4; ++g)
            atomicAdd(&msg_agg[(size_t)dg[g] * 64 + nt * 16 + mcol], mv[nt][g]);

    // ---- GEMM3: p = silu(m @ Wx1 + bx1) ----
    f32x4 acc3[4];
    #pragma unroll
    for (int nt = 0; nt < 4; ++nt) {
        float bv = bx1[nt * 16 + mcol];
        acc3[nt] = (f32x4){bv, bv, bv, bv};
    }
    const bf16_t* Bg3 = Bg + 9 * 4 * 64 * 8;
    #pragma unroll
    for (int c = 0; c < 2; ++c) {
        bf16x8 af = *(const bf16x8*)(aBase2 + c * 32);
        #pragma unroll
        for (int nt = 0; nt < 4; ++nt) {
            bf16x8 bfr = *(const bf16x8*)(Bg3 + ((size_t)(c * 4 + nt) * 64 + lane) * 8);
            acc3[nt] = __builtin_amdgcn_mfma_f32_16x16x32_bf16(af, bfr, acc3[nt], 0, 0, 0);
        }
    }

    // ---- cw = tanh(silu(p) . Wx2 + bx2); coord atomic (ligand dst only) ----
    const float bx2v = bx2[0];
    float s[4] = {0.f, 0.f, 0.f, 0.f};
    #pragma unroll
    for (int nt = 0; nt < 4; ++nt) {
        float w = Wx2[nt * 16 + mcol];
        #pragma unroll
        for (int g = 0; g < 4; ++g) s[g] = fmaf(silu_f(acc3[nt][g]), w, s[g]);
    }
    #pragma unroll
    for (int g = 0; g < 4; ++g) {
        float p = s[g];
        #pragma unroll
        for (int off = 1; off < 16; off <<= 1) p += __shfl_xor(p, off, 64);
        const float cw = tanh_f(p + bx2v);
        const int d = dg[g];
        if (d < N_LIG && mcol < 3)
            atomicAdd(&coord_agg[d * 3 + mcol], dfL[(mrow0 + g) * 4 + mcol] * cw);
    }
}

// ---------------- per-layer node update (f32 VALU; small vs edge work) ----------------
__global__ __launch_bounds__(256) void k_node(
    float* __restrict__ h, float* __restrict__ x,
    const float* __restrict__ msg, const float* __restrict__ coord,
    const float* __restrict__ Wh1p, const float* __restrict__ bh1,
    const float* __restrict__ Wh2p, const float* __restrict__ bh2) {
    __shared__ __align__(16) float lds[4][TE * 128];
    const int lane = threadIdx.x & 63;
    const int wave = threadIdx.x >> 6;
    float* inL = lds[wave];
    const int base = (blockIdx.x * 4 + wave) * TE;

    for (int r = 0; r < TE; ++r) {
        const int n = base + r;
        inL[r * 128 + lane] = h[n * 64 + lane];
        inL[r * 128 + 64 + lane] = msg[n * 64 + lane];
    }
    __syncthreads();

    float acc[TE];
    #pragma unroll
    for (int r = 0; r < TE; ++r) acc[r] = bh1[lane];
    for (int c = 0; c < 32; ++c) {
        const float4 w = *(const float4*)(Wh1p + (c * 64 + lane) * 4);
        #pragma unroll
        for (int r = 0; r < TE; ++r) {
            const float4 v = *(const float4*)(inL + r * 128 + c * 4);
            acc[r] = fmaf(v.x, w.x, fmaf(v.y, w.y, fmaf(v.z, w.z, fmaf(v.w, w.w, acc[r]))));
        }
    }
    __syncthreads();
    #pragma unroll
    for (int r = 0; r < TE; ++r) inL[r * 64 + lane] = silu_f(acc[r]);
    __syncthreads();

    float acc2[TE];
    #pragma unroll
    for (int r = 0; r < TE; ++r) acc2[r] = bh2[lane];
    for (int c = 0; c < 16; ++c) {
        const float4 w = *(const float4*)(Wh2p + (c * 64 + lane) * 4);
        #pragma unroll
        for (int r = 0; r < TE; ++r) {
            const float4 v = *(const float4*)(inL + r * 64 + c * 4);
            acc2[r] = fmaf(v.x, w.x, fmaf(v.y, w.y, fmaf(v.z, w.z, fmaf(v.w, w.w, acc2[r]))));
        }
    }
    for (int r = 0; r < TE; ++r) {
        const int n = base + r;
        h[n * 64 + lane] += acc2[r];
        if (lane < 3 && n < N_LIG) x[n * 3 + lane] += coord[n * 3 + lane];
    }
}

// ---------------- output head ----------------
__global__ void k_out(const float* __restrict__ h, const float* __restrict__ x,
                      const float* __restrict__ lig_x,
                      const float* __restrict__ oW1, const float* __restrict__ ob1,
                      const float* __restrict__ oW2, const float* __restrict__ ob2,
                      float* __restrict__ out) {
    int gid = blockIdx.x * blockDim.x + threadIdx.x;
    int n = gid >> 6;
    int lane = gid & 63;
    if (n >= N_LIG) return;
    float hv = h[n * 64 + lane];
    float a = ob1[lane];
    #pragma unroll
    for (int k = 0; k < 64; ++k) a = fmaf(__shfl(hv, k, 64), oW1[k * 64 + lane], a);
    float p = silu_f(a) * oW2[lane];
    #pragma unroll
    for (int off = 32; off > 0; off >>= 1) p += __shfl_xor(p, off, 64);
    float scale = p + ob2[0];
    if (lane < 3) out[n * 3 + lane] = scale * (x[n * 3 + lane] - lig_x[n * 3 + lane]);
}

// ---------------- launch ----------------
extern "C" void kernel_launch(void* const* d_in, const int* in_sizes, int n_in,
                              void* d_out, int out_size, void* d_ws, size_t ws_size,
                              hipStream_t stream) {
    const float* lig_x      = (const float*)d_in[0];
    const float* lig_h      = (const float*)d_in[1];
    const float* poc_x      = (const float*)d_in[2];
    const float* poc_h      = (const float*)d_in[3];
    const int*   lig_ei     = (const int*)d_in[4];
    const float* lig_attr   = (const float*)d_in[5];
    const int*   poc_ei     = (const int*)d_in[6];
    const float* poc_attr   = (const float*)d_in[7];
    const int*   cross_ei   = (const int*)d_in[8];
    const float* cross_attr = (const float*)d_in[9];
    const float* t          = (const float*)d_in[10];
    const float* lig_emb_W  = (const float*)d_in[11];
    const float* lig_emb_b  = (const float*)d_in[12];
    const float* poc_emb_W  = (const float*)d_in[13];
    const float* poc_emb_b  = (const float*)d_in[14];
    const float* lig_ee_W   = (const float*)d_in[15];
    const float* lig_ee_b   = (const float*)d_in[16];
    const float* poc_ee_W   = (const float*)d_in[17];
    const float* poc_ee_b   = (const float*)d_in[18];
    const float* cross_ee_W = (const float*)d_in[19];
    const float* cross_ee_b = (const float*)d_in[20];
    const float* phi_e_W1   = (const float*)d_in[21];
    const float* phi_e_b1   = (const float*)d_in[22];
    const float* phi_e_W2   = (const float*)d_in[23];
    const float* phi_e_b2   = (const float*)d_in[24];
    const float* phi_x_W1   = (const float*)d_in[25];
    const float* phi_x_b1   = (const float*)d_in[26];
    const float* phi_x_W2   = (const float*)d_in[27];
    const float* phi_x_b2   = (const float*)d_in[28];
    const float* phi_h_W1   = (const float*)d_in[29];
    const float* phi_h_b1   = (const float*)d_in[30];
    const float* phi_h_W2   = (const float*)d_in[31];
    const float* phi_h_b2   = (const float*)d_in[32];
    const float* out_W1     = (const float*)d_in[33];
    const float* out_b1     = (const float*)d_in[34];
    const float* out_W2     = (const float*)d_in[35];
    const float* out_b2     = (const float*)d_in[36];

    // workspace (floats): h | msg | x | coord | Wp(node f32 pack) | Bg(bf16 frag pack) | srcA | dstA
    float*  h     = (float*)d_ws;
    float*  msg   = h + (size_t)N_TOT * 64;
    float*  xx    = msg + (size_t)N_TOT * 64;
    float*  coord = xx + (size_t)N_TOT * 3;
    float*  Wp    = coord + (size_t)N_TOT * 3;
    bf16_t* Bg    = (bf16_t*)(Wp + 4 * 48 * 256);
    int*    srcA  = (int*)((char*)Bg + (size_t)4 * BG_PER_LAYER * 2);
    int*    dstA  = srcA + E_TOT;

    k_build_edges<<<E_TOT / 256, 256, 0, stream>>>(lig_ei, poc_ei, cross_ei, srcA, dstA);
    k_pack_weights<<<(4 * 48 * 256) / 256, 256, 0, stream>>>(phi_h_W1, phi_h_W2, Wp);
    k_pack_wb<<<(4 * 11 * 4 * 64 + 255) / 256, 256, 0, stream>>>(phi_e_W1, phi_e_W2, phi_x_W1, Bg);
    k_embed<<<(N_TOT * 64) / 256, 256, 0, stream>>>(
        lig_x, lig_h, poc_x, poc_h, t, lig_emb_W, lig_emb_b, poc_emb_W, poc_emb_b, h, xx);

    for (int l = 0; l < 4; ++l) {
        hipMemsetAsync(msg, 0, (size_t)N_TOT * 64 * sizeof(float), stream);
        hipMemsetAsync(coord, 0, (size_t)N_TOT * 3 * sizeof(float), stream);
        const float* Wl = Wp + (size_t)l * 48 * 256;
        k_edge_mfma<<<E_TOT / 64, 256, 0, stream>>>(
            h, xx, srcA, dstA, lig_attr, poc_attr, cross_attr,
            lig_ee_W, lig_ee_b, poc_ee_W, poc_ee_b, cross_ee_W, cross_ee_b,
            Bg + (size_t)l * BG_PER_LAYER,
            phi_e_b1 + l * 64, phi_e_b2 + l * 64, phi_x_b1 + l * 64,
            phi_x_W2 + l * 64, phi_x_b2 + l,
            msg, coord);
        k_node<<<N_TOT / 64, 256, 0, stream>>>(
            h, xx, msg, coord,
            Wl, phi_h_b1 + l * 64,
            Wl + 32 * 256, phi_h_b2 + l * 64);
    }

    k_out<<<(N_LIG * 64) / 256, 256, 0, stream>>>(
        h, xx, lig_x, out_W1, out_b1, out_W2, out_b2, (float*)d_out);
}

// Round 3
// 1005.553 us; speedup vs baseline: 4.4457x; 2.5262x over previous
//
#include <hip/hip_runtime.h>

#define N_LIG 16384
#define M_POC 32768
#define N_TOT (N_LIG + M_POC)           // 49152
#define E_LIG 163840
#define E_POC 327680
#define E_CROSS (N_LIG * 8)             // 131072
#define E_TOT (E_LIG + E_POC + E_CROSS) // 622592
#define TE 16                           // edges/nodes per wave tile

typedef __bf16 bf16_t;
typedef bf16_t bf16x8 __attribute__((ext_vector_type(8)));
typedef bf16_t bf16x4 __attribute__((ext_vector_type(4)));
typedef bf16_t bf16x2 __attribute__((ext_vector_type(2)));
typedef float f32x4 __attribute__((ext_vector_type(4)));

// e_in row: [h_src(0..63) | h_dst(64..127) | dist(128) | zero(129..131) | attr(132..147) | zero(..159)]
#define S1 168   // bf16 stride; 168*2=336B, %16==0 (b128-aligned rows), non-pow2 (bank spread)
#define S2 72    // m rows
// per-wave LDS: einA 16*168*2=5376 | mA 16*72*2=2304 | dfL 16*4*4=256  => 7936 B; 31744/block
#define WAVE_BYTES 7936

__device__ __forceinline__ float silu_f(float v) { return v / (1.0f + __expf(-v)); }

__device__ __forceinline__ float tanh_f(float v) {
    float a = fabsf(v);
    float t = __expf(-2.0f * a);
    float r = (1.0f - t) / (1.0f + t);
    return copysignf(r, v);
}

__device__ __forceinline__ void atomic_add_f32(float* p, float v) {
    __hip_atomic_fetch_add(p, v, __ATOMIC_RELAXED, __HIP_MEMORY_SCOPE_AGENT);
}

// ---------------- setup kernels ----------------

__global__ void k_build_edges(const int* __restrict__ lig_ei, const int* __restrict__ poc_ei,
                              const int* __restrict__ cross_ei,
                              int* __restrict__ srcA, int* __restrict__ dstA) {
    int e = blockIdx.x * blockDim.x + threadIdx.x;
    if (e >= E_TOT) return;
    int s, d;
    if (e < E_LIG) {
        s = lig_ei[e];
        d = lig_ei[E_LIG + e];
    } else if (e < E_LIG + E_POC) {
        int i = e - E_LIG;
        s = poc_ei[i] + N_LIG;
        d = poc_ei[E_POC + i] + N_LIG;
    } else {
        int i = e - E_LIG - E_POC;
        s = cross_ei[i] + N_LIG;
        d = cross_ei[E_CROSS + i];
    }
    srcA[e] = s;
    dstA[e] = d;
}

__global__ void k_hist(const int* __restrict__ dstA, int* __restrict__ cnt) {
    int e = blockIdx.x * blockDim.x + threadIdx.x;
    if (e < E_TOT) atomicAdd(&cnt[dstA[e]], 1);
}

// single block, 1024 threads, 48 bins per thread
__global__ __launch_bounds__(1024) void k_scan(const int* __restrict__ cnt,
                                               int* __restrict__ rowptr,
                                               int* __restrict__ cursor) {
    __shared__ int sums[1024];
    int tid = threadIdx.x;
    int local[48];
    int s = 0;
    for (int i = 0; i < 48; ++i) { local[i] = s; s += cnt[tid * 48 + i]; }
    sums[tid] = s;
    __syncthreads();
    for (int off = 1; off < 1024; off <<= 1) {
        int v = (tid >= off) ? sums[tid - off] : 0;
        __syncthreads();
        sums[tid] += v;
        __syncthreads();
    }
    int base = (tid == 0) ? 0 : sums[tid - 1];
    for (int i = 0; i < 48; ++i) {
        int v = base + local[i];
        int idx = tid * 48 + i;
        rowptr[idx] = v;
        cursor[idx] = v;
    }
    if (tid == 1023) rowptr[N_TOT] = sums[1023];
}

__global__ void k_scatter(const int* __restrict__ dstA, int* __restrict__ cursor,
                          int* __restrict__ sortedPos) {
    int e = blockIdx.x * blockDim.x + threadIdx.x;
    if (e < E_TOT) sortedPos[e] = atomicAdd(&cursor[dstA[e]], 1);
}

// Fold edge-embedding into phi_e_W1: effW[lt][160][64], beff[lt][64], lt = l*3+t
__global__ void k_fold(const float* __restrict__ W1, const float* __restrict__ b1,
                       const float* __restrict__ ligW, const float* __restrict__ ligB,
                       const float* __restrict__ pocW, const float* __restrict__ pocB,
                       const float* __restrict__ crossW, const float* __restrict__ crossB,
                       float* __restrict__ effW, float* __restrict__ beff) {
    int tid = blockIdx.x * blockDim.x + threadIdx.x;
    const int total = 4 * 3 * 160 * 64;
    if (tid < total) {
        int j = tid & 63;
        int rem = tid >> 6;
        int row = rem % 160;
        int lt = rem / 160;
        int l = lt / 3, t = lt % 3;
        const float* W1l = W1 + l * 193 * 64;
        float v = 0.0f;
        if (row < 129) v = W1l[row * 64 + j];
        else if (row >= 132 && row < 148) {
            int k = row - 132;
            const float* We; int K;
            if (t == 0) { We = ligW; K = 6; }
            else if (t == 1) { We = pocW; K = 16; }
            else { We = crossW; K = 16; }
            if (k < K) {
                float a = 0.0f;
                for (int q = 0; q < 64; ++q) a = fmaf(We[k * 64 + q], W1l[(129 + q) * 64 + j], a);
                v = a;
            }
        }
        effW[tid] = v;
    } else if (tid < total + 4 * 3 * 64) {
        int u = tid - total;
        int j = u & 63;
        int lt = u >> 6;
        int l = lt / 3, t = lt % 3;
        const float* W1l = W1 + l * 193 * 64;
        const float* Be = (t == 0) ? ligB : ((t == 1) ? pocB : crossB);
        float v = b1[l * 64 + j];
        for (int q = 0; q < 64; ++q) v = fmaf(Be[q], W1l[(129 + q) * 64 + j], v);
        beff[u] = v;
    }
}

// Pack effW into GEMM1 B-fragments: Bg1[((lt*5+c)*4+nt)*512 + lane*8 + j]
__global__ void k_pack_g1(const float* __restrict__ effW, bf16_t* __restrict__ Bg1) {
    int tid = blockIdx.x * blockDim.x + threadIdx.x;
    if (tid >= 12 * 5 * 4 * 64) return;
    int lt = tid / 1280;
    int rem = tid - lt * 1280;
    int c = rem >> 8;
    int nt = (rem >> 6) & 3;
    int lane = rem & 63;
    int col = nt * 16 + (lane & 15);
    int k0 = c * 32 + (lane >> 4) * 8;
    #pragma unroll
    for (int j = 0; j < 8; ++j)
        Bg1[(size_t)tid * 8 + j] = (bf16_t)effW[lt * 10240 + (k0 + j) * 64 + col];
}

// Pack GEMM2 (phi_e_W2) + GEMM3 (phi_x_W1) B-frags: Bg23[((l*16 + c*4 + nt)*64 + lane)*8 + j]
__global__ void k_pack_g23(const float* __restrict__ phi_e_W2, const float* __restrict__ phi_x_W1,
                           bf16_t* __restrict__ Bg23) {
    int tid = blockIdx.x * blockDim.x + threadIdx.x;
    if (tid >= 4 * 4 * 4 * 64) return;
    int lane = tid & 63;
    int nt = (tid >> 6) & 3;
    int c = (tid >> 8) & 3;
    int l = tid >> 10;
    const float* W = (c < 2) ? (phi_e_W2 + l * 4096) : (phi_x_W1 + l * 4096);
    int kb = (c & 1) * 32;
    int col = nt * 16 + (lane & 15);
    int k0 = kb + (lane >> 4) * 8;
    #pragma unroll
    for (int j = 0; j < 8; ++j)
        Bg23[(size_t)tid * 8 + j] = (bf16_t)W[(k0 + j) * 64 + col];
}

// f32 k-chunked pack for node MLP: Wh1(32 chunks) Wh2(16) per layer
__global__ void k_pack_weights(const float* __restrict__ phi_h_W1,
                               const float* __restrict__ phi_h_W2,
                               float* __restrict__ Wp) {
    int idx = blockIdx.x * blockDim.x + threadIdx.x;
    if (idx >= 4 * 48 * 256) return;
    int l = idx / (48 * 256);
    int rem = idx - l * 48 * 256;
    int c = rem / 256;
    int q = rem - c * 256;
    int j = q >> 2;
    int kk = q & 3;
    const float* W; int Ksrc; int k4;
    if (c < 32) { W = phi_h_W1 + l * 128 * 64; Ksrc = 128; k4 = c; }
    else        { W = phi_h_W2 + l * 64 * 64;  Ksrc = 64;  k4 = c - 32; }
    int k = k4 * 4 + kk;
    Wp[idx] = (k < Ksrc) ? W[k * 64 + j] : 0.0f;
}

__global__ void k_embed(const float* __restrict__ lig_x, const float* __restrict__ lig_h,
                        const float* __restrict__ poc_x, const float* __restrict__ poc_h,
                        const float* __restrict__ t,
                        const float* __restrict__ ligW, const float* __restrict__ ligB,
                        const float* __restrict__ pocW, const float* __restrict__ pocB,
                        float* __restrict__ h, float* __restrict__ x) {
    int gid = blockIdx.x * blockDim.x + threadIdx.x;
    int n = gid >> 6;
    int lane = gid & 63;
    if (n >= N_TOT) return;
    if (n < N_LIG) {
        float a = ligB[lane];
        #pragma unroll
        for (int k = 0; k < 17; ++k) a = fmaf(lig_h[n * 17 + k], ligW[k * 64 + lane], a);
        a = fmaf(t[0], ligW[17 * 64 + lane], a);
        h[n * 64 + lane] = a;
        if (lane < 3) x[n * 3 + lane] = lig_x[n * 3 + lane];
    } else {
        int p = n - N_LIG;
        float a = pocB[lane];
        #pragma unroll
        for (int k = 0; k < 29; ++k) a = fmaf(poc_h[p * 29 + k], pocW[k * 64 + lane], a);
        h[n * 64 + lane] = a;
        if (lane < 3) x[n * 3 + lane] = poc_x[p * 3 + lane];
    }
}

// ---------------- per-layer MFMA edge kernel ----------------
// Block = 256 (4 waves); wave = 16 edges (original order; tile type-uniform).
// Writes per-edge message m (bf16) to mBuf at dst-sorted position; coord via few atomics.
__global__ __launch_bounds__(256) void k_edge_mfma(
    const float* __restrict__ hG, const float* __restrict__ x,
    const int* __restrict__ srcA, const int* __restrict__ dstA,
    const int* __restrict__ sortedPos,
    const float* __restrict__ lig_attr, const float* __restrict__ poc_attr,
    const float* __restrict__ cross_attr,
    const bf16_t* __restrict__ Bg1L,   // + t*5*4*512 inside
    const float* __restrict__ beffL,   // + t*64 inside
    const bf16_t* __restrict__ Bg23L,
    const float* __restrict__ b2, const float* __restrict__ bx1,
    const float* __restrict__ Wx2, const float* __restrict__ bx2,
    bf16_t* __restrict__ mBuf, float* __restrict__ coord_agg) {
    __shared__ __align__(16) char lds[4 * WAVE_BYTES];
    const int lane = threadIdx.x & 63;
    const int wave = threadIdx.x >> 6;
    bf16_t* einA = (bf16_t*)(lds + wave * WAVE_BYTES);
    bf16_t* mA   = (bf16_t*)(lds + wave * WAVE_BYTES + 5376);
    float*  dfL  = (float*)(lds + wave * WAVE_BYTES + 5376 + 2304);
    const int base = (blockIdx.x * 4 + wave) * TE;

    // edge type (tile-uniform)
    int t; const float* attrBase;
    if (base < E_LIG) { t = 0; attrBase = lig_attr + (size_t)base * 6; }
    else if (base < E_LIG + E_POC) { t = 1; attrBase = poc_attr + (size_t)(base - E_LIG) * 16; }
    else { t = 2; attrBase = cross_attr + (size_t)(base - E_LIG - E_POC) * 16; }

    // per-lane edge metadata for edge (lane&15)
    const int e16 = base + (lane & 15);
    const int sv = srcA[e16];
    const int dv = dstA[e16];
    const int sp = sortedPos[e16];

    // ---- zero cols 128..159 of all rows (1 instr) ----
    {
        bf16x8 z = {(bf16_t)0.f, (bf16_t)0.f, (bf16_t)0.f, (bf16_t)0.f,
                    (bf16_t)0.f, (bf16_t)0.f, (bf16_t)0.f, (bf16_t)0.f};
        *(bf16x8*)(einA + (lane >> 2) * S1 + 128 + (lane & 3) * 8) = z;
    }

    // ---- h_src / h_dst gathers: 4 rows per instruction, float4 per lane ----
    #pragma unroll
    for (int i = 0; i < 4; ++i) {
        const int row = i * 4 + (lane >> 4);
        const int s = __shfl(sv, row, 64);
        const int d = __shfl(dv, row, 64);
        float4 fs = *(const float4*)(hG + (size_t)s * 64 + (lane & 15) * 4);
        float4 fd = *(const float4*)(hG + (size_t)d * 64 + (lane & 15) * 4);
        bf16x4 hs = {(bf16_t)fs.x, (bf16_t)fs.y, (bf16_t)fs.z, (bf16_t)fs.w};
        bf16x4 hd = {(bf16_t)fd.x, (bf16_t)fd.y, (bf16_t)fd.z, (bf16_t)fd.w};
        *(bf16x4*)(einA + row * S1 + (lane & 15) * 4) = hs;
        *(bf16x4*)(einA + row * S1 + 64 + (lane & 15) * 4) = hd;
    }

    // ---- x / dist: lane r<16 handles edge r ----
    if (lane < 16) {
        const float* xs = x + (size_t)sv * 3;
        const float* xd = x + (size_t)dv * 3;
        float d0 = xs[0] - xd[0];
        float d1 = xs[1] - xd[1];
        float d2 = xs[2] - xd[2];
        float dist = (d0 * d0 + d1 * d1 + d2 * d2) * 0.01f;
        einA[lane * S1 + 128] = (bf16_t)dist;
        *(float4*)(dfL + lane * 4) = (float4){d0, d1, d2, dist};
    }

    // ---- attr tile: cols 132.. (raw attrs; Wee folded into W1eff) ----
    {
        const int r = lane >> 2, q = lane & 3;
        if (t == 0) {
            if (q < 3) {
                float2 a = *(const float2*)(attrBase + r * 6 + q * 2);
                bf16x2 av = {(bf16_t)a.x, (bf16_t)a.y};
                *(bf16x2*)(einA + r * S1 + 132 + q * 2) = av;
            }
        } else {
            float4 a = *(const float4*)(attrBase + r * 16 + q * 4);
            bf16x4 av = {(bf16_t)a.x, (bf16_t)a.y, (bf16_t)a.z, (bf16_t)a.w};
            *(bf16x4*)(einA + r * S1 + 132 + q * 4) = av;
        }
    }
    __syncthreads();

    const int mcol = lane & 15;
    const int mrow0 = (lane >> 4) * 4;
    const int kgrp = lane >> 4;

    // ---- GEMM1: m1 = silu(e_in @ W1eff + beff) : 5 k-chunks x 4 n-tiles ----
    const bf16_t* Bg1 = Bg1L + (size_t)t * 5 * 4 * 512;
    const float* beff = beffL + t * 64;
    f32x4 acc1[4];
    #pragma unroll
    for (int nt = 0; nt < 4; ++nt) {
        float bv = beff[nt * 16 + mcol];
        acc1[nt] = (f32x4){bv, bv, bv, bv};
    }
    const bf16_t* aBase = einA + mcol * S1 + kgrp * 8;
    #pragma unroll
    for (int c = 0; c < 5; ++c) {
        bf16x8 af = *(const bf16x8*)(aBase + c * 32);
        #pragma unroll
        for (int nt = 0; nt < 4; ++nt) {
            bf16x8 bfr = *(const bf16x8*)(Bg1 + ((size_t)(c * 4 + nt) * 64 + lane) * 8);
            acc1[nt] = __builtin_amdgcn_mfma_f32_16x16x32_bf16(af, bfr, acc1[nt], 0, 0, 0);
        }
    }
    __syncthreads();
    #pragma unroll
    for (int nt = 0; nt < 4; ++nt)
        #pragma unroll
        for (int g = 0; g < 4; ++g)
            mA[(mrow0 + g) * S2 + nt * 16 + mcol] = (bf16_t)silu_f(acc1[nt][g]);
    __syncthreads();

    // ---- GEMM2: m = silu(m1 @ W2 + b2) ----
    f32x4 acc2[4];
    #pragma unroll
    for (int nt = 0; nt < 4; ++nt) {
        float bv = b2[nt * 16 + mcol];
        acc2[nt] = (f32x4){bv, bv, bv, bv};
    }
    const bf16_t* aBase2 = mA + mcol * S2 + kgrp * 8;
    #pragma unroll
    for (int c = 0; c < 2; ++c) {
        bf16x8 af = *(const bf16x8*)(aBase2 + c * 32);
        #pragma unroll
        for (int nt = 0; nt < 4; ++nt) {
            bf16x8 bfr = *(const bf16x8*)(Bg23L + ((size_t)(c * 4 + nt) * 64 + lane) * 8);
            acc2[nt] = __builtin_amdgcn_mfma_f32_16x16x32_bf16(af, bfr, acc2[nt], 0, 0, 0);
        }
    }
    float mv[4][4];
    #pragma unroll
    for (int nt = 0; nt < 4; ++nt)
        #pragma unroll
        for (int g = 0; g < 4; ++g)
            mv[nt][g] = silu_f(acc2[nt][g]);
    __syncthreads();
    #pragma unroll
    for (int nt = 0; nt < 4; ++nt)
        #pragma unroll
        for (int g = 0; g < 4; ++g)
            mA[(mrow0 + g) * S2 + nt * 16 + mcol] = (bf16_t)mv[nt][g];
    __syncthreads();

    // ---- store m to mBuf at dst-sorted rows (bf16, no atomics) ----
    int pos_g[4];
    #pragma unroll
    for (int g = 0; g < 4; ++g) pos_g[g] = __shfl(sp, mrow0 + g, 64);
    #pragma unroll
    for (int nt = 0; nt < 4; ++nt)
        #pragma unroll
        for (int g = 0; g < 4; ++g)
            mBuf[(size_t)pos_g[g] * 64 + nt * 16 + mcol] = (bf16_t)mv[nt][g];

    // ---- GEMM3: p = silu(m @ Wx1 + bx1) ----
    f32x4 acc3[4];
    #pragma unroll
    for (int nt = 0; nt < 4; ++nt) {
        float bv = bx1[nt * 16 + mcol];
        acc3[nt] = (f32x4){bv, bv, bv, bv};
    }
    const bf16_t* Bg3 = Bg23L + (size_t)2 * 4 * 512;
    #pragma unroll
    for (int c = 0; c < 2; ++c) {
        bf16x8 af = *(const bf16x8*)(aBase2 + c * 32);
        #pragma unroll
        for (int nt = 0; nt < 4; ++nt) {
            bf16x8 bfr = *(const bf16x8*)(Bg3 + ((size_t)(c * 4 + nt) * 64 + lane) * 8);
            acc3[nt] = __builtin_amdgcn_mfma_f32_16x16x32_bf16(af, bfr, acc3[nt], 0, 0, 0);
        }
    }

    // ---- cw = tanh(silu(p) . Wx2 + bx2); coord atomics (ligand dst only, 3 lanes/edge) ----
    const float bx2v = bx2[0];
    float s[4] = {0.f, 0.f, 0.f, 0.f};
    #pragma unroll
    for (int nt = 0; nt < 4; ++nt) {
        float w = Wx2[nt * 16 + mcol];
        #pragma unroll
        for (int g = 0; g < 4; ++g) s[g] = fmaf(silu_f(acc3[nt][g]), w, s[g]);
    }
    #pragma unroll
    for (int g = 0; g < 4; ++g) {
        float p = s[g];
        #pragma unroll
        for (int off = 1; off < 16; off <<= 1) p += __shfl_xor(p, off, 64);
        const float cw = tanh_f(p + bx2v);
        const int d = __shfl(dv, mrow0 + g, 64);
        if (d < N_LIG && mcol < 3)
            atomic_add_f32(&coord_agg[d * 3 + mcol], dfL[(mrow0 + g) * 4 + mcol] * cw);
    }
}

// ---------------- per-layer node update: gather msg from mBuf ranges + MLP ----------------
__global__ __launch_bounds__(256) void k_node(
    float* __restrict__ h, float* __restrict__ x,
    const bf16_t* __restrict__ mBuf, const int* __restrict__ rowptr,
    const float* __restrict__ coord,
    const float* __restrict__ Wh1p, const float* __restrict__ bh1,
    const float* __restrict__ Wh2p, const float* __restrict__ bh2) {
    __shared__ __align__(16) float lds[4][TE * 128];
    const int lane = threadIdx.x & 63;
    const int wave = threadIdx.x >> 6;
    float* inL = lds[wave];
    const int base = (blockIdx.x * 4 + wave) * TE;

    // h staging: contiguous, 4x float4 per lane
    #pragma unroll
    for (int i = 0; i < 4; ++i) {
        int fidx = i * 256 + lane * 4;
        float4 v = *(const float4*)(h + (size_t)base * 64 + fidx);
        *(float4*)(inL + (fidx >> 6) * 128 + (fidx & 63)) = v;
    }

    // msg gather: node r's edges are contiguous [rp0, rp1) in mBuf
    const int n16 = base + (lane & 15);
    const int rp0 = rowptr[n16];
    const int rp1 = rowptr[n16 + 1];
    for (int r = 0; r < TE; ++r) {
        const int s0 = __shfl(rp0, r, 64);
        const int s1 = __shfl(rp1, r, 64);
        float acc = 0.0f;
        int i = s0;
        for (; i + 1 < s1; i += 2) {
            float a0 = (float)mBuf[(size_t)i * 64 + lane];
            float a1 = (float)mBuf[(size_t)(i + 1) * 64 + lane];
            acc += a0 + a1;
        }
        if (i < s1) acc += (float)mBuf[(size_t)i * 64 + lane];
        inL[r * 128 + 64 + lane] = acc;
    }
    __syncthreads();

    float acc[TE];
    #pragma unroll
    for (int r = 0; r < TE; ++r) acc[r] = bh1[lane];
    for (int c = 0; c < 32; ++c) {
        const float4 w = *(const float4*)(Wh1p + (c * 64 + lane) * 4);
        #pragma unroll
        for (int r = 0; r < TE; ++r) {
            const float4 v = *(const float4*)(inL + r * 128 + c * 4);
            acc[r] = fmaf(v.x, w.x, fmaf(v.y, w.y, fmaf(v.z, w.z, fmaf(v.w, w.w, acc[r]))));
        }
    }
    __syncthreads();
    #pragma unroll
    for (int r = 0; r < TE; ++r) inL[r * 64 + lane] = silu_f(acc[r]);
    __syncthreads();

    float acc2[TE];
    #pragma unroll
    for (int r = 0; r < TE; ++r) acc2[r] = bh2[lane];
    for (int c = 0; c < 16; ++c) {
        const float4 w = *(const float4*)(Wh2p + (c * 64 + lane) * 4);
        #pragma unroll
        for (int r = 0; r < TE; ++r) {
            const float4 v = *(const float4*)(inL + r * 64 + c * 4);
            acc2[r] = fmaf(v.x, w.x, fmaf(v.y, w.y, fmaf(v.z, w.z, fmaf(v.w, w.w, acc2[r]))));
        }
    }
    for (int r = 0; r < TE; ++r) {
        const int n = base + r;
        h[n * 64 + lane] += acc2[r];
        if (lane < 3 && n < N_LIG) x[n * 3 + lane] += coord[n * 3 + lane];
    }
}

// ---------------- output head ----------------
__global__ void k_out(const float* __restrict__ h, const float* __restrict__ x,
                      const float* __restrict__ lig_x,
                      const float* __restrict__ oW1, const float* __restrict__ ob1,
                      const float* __restrict__ oW2, const float* __restrict__ ob2,
                      float* __restrict__ out) {
    int gid = blockIdx.x * blockDim.x + threadIdx.x;
    int n = gid >> 6;
    int lane = gid & 63;
    if (n >= N_LIG) return;
    float hv = h[n * 64 + lane];
    float a = ob1[lane];
    #pragma unroll
    for (int k = 0; k < 64; ++k) a = fmaf(__shfl(hv, k, 64), oW1[k * 64 + lane], a);
    float p = silu_f(a) * oW2[lane];
    #pragma unroll
    for (int off = 32; off > 0; off >>= 1) p += __shfl_xor(p, off, 64);
    float scale = p + ob2[0];
    if (lane < 3) out[n * 3 + lane] = scale * (x[n * 3 + lane] - lig_x[n * 3 + lane]);
}

// ---------------- launch ----------------
extern "C" void kernel_launch(void* const* d_in, const int* in_sizes, int n_in,
                              void* d_out, int out_size, void* d_ws, size_t ws_size,
                              hipStream_t stream) {
    const float* lig_x      = (const float*)d_in[0];
    const float* lig_h      = (const float*)d_in[1];
    const float* poc_x      = (const float*)d_in[2];
    const float* poc_h      = (const float*)d_in[3];
    const int*   lig_ei     = (const int*)d_in[4];
    const float* lig_attr   = (const float*)d_in[5];
    const int*   poc_ei     = (const int*)d_in[6];
    const float* poc_attr   = (const float*)d_in[7];
    const int*   cross_ei   = (const int*)d_in[8];
    const float* cross_attr = (const float*)d_in[9];
    const float* t          = (const float*)d_in[10];
    const float* lig_emb_W  = (const float*)d_in[11];
    const float* lig_emb_b  = (const float*)d_in[12];
    const float* poc_emb_W  = (const float*)d_in[13];
    const float* poc_emb_b  = (const float*)d_in[14];
    const float* lig_ee_W   = (const float*)d_in[15];
    const float* lig_ee_b   = (const float*)d_in[16];
    const float* poc_ee_W   = (const float*)d_in[17];
    const float* poc_ee_b   = (const float*)d_in[18];
    const float* cross_ee_W = (const float*)d_in[19];
    const float* cross_ee_b = (const float*)d_in[20];
    const float* phi_e_W1   = (const float*)d_in[21];
    const float* phi_e_b1   = (const float*)d_in[22];
    const float* phi_e_W2   = (const float*)d_in[23];
    const float* phi_e_b2   = (const float*)d_in[24];
    const float* phi_x_W1   = (const float*)d_in[25];
    const float* phi_x_b1   = (const float*)d_in[26];
    const float* phi_x_W2   = (const float*)d_in[27];
    const float* phi_x_b2   = (const float*)d_in[28];
    const float* phi_h_W1   = (const float*)d_in[29];
    const float* phi_h_b1   = (const float*)d_in[30];
    const float* phi_h_W2   = (const float*)d_in[31];
    const float* phi_h_b2   = (const float*)d_in[32];
    const float* out_W1     = (const float*)d_in[33];
    const float* out_b1     = (const float*)d_in[34];
    const float* out_W2     = (const float*)d_in[35];
    const float* out_b2     = (const float*)d_in[36];

    // ---- workspace carve (256B aligned chunks) ----
    char* p = (char*)d_ws;
    auto carve = [&](size_t bytes) { char* r = p; p += (bytes + 255) & ~(size_t)255; return r; };
    float*  h      = (float*)carve((size_t)N_TOT * 64 * 4);
    float*  xx     = (float*)carve((size_t)N_TOT * 3 * 4);
    float*  coord  = (float*)carve((size_t)N_TOT * 3 * 4);
    float*  Wp     = (float*)carve((size_t)4 * 48 * 256 * 4);
    float*  effW   = (float*)carve((size_t)12 * 160 * 64 * 4);
    float*  beff   = (float*)carve((size_t)12 * 64 * 4);
    bf16_t* Bg1    = (bf16_t*)carve((size_t)12 * 5 * 4 * 512 * 2);
    bf16_t* Bg23   = (bf16_t*)carve((size_t)4 * 16 * 512 * 2);
    int*    srcA   = (int*)carve((size_t)E_TOT * 4);
    int*    dstA   = (int*)carve((size_t)E_TOT * 4);
    int*    sortedPos = (int*)carve((size_t)E_TOT * 4);
    int*    cnt    = (int*)carve((size_t)N_TOT * 4);
    int*    cursor = (int*)carve((size_t)N_TOT * 4);
    int*    rowptr = (int*)carve((size_t)(N_TOT + 1) * 4);
    bf16_t* mBuf   = (bf16_t*)carve((size_t)E_TOT * 64 * 2);

    // ---- setup (once per launch) ----
    k_build_edges<<<E_TOT / 256, 256, 0, stream>>>(lig_ei, poc_ei, cross_ei, srcA, dstA);
    hipMemsetAsync(cnt, 0, (size_t)N_TOT * 4, stream);
    k_hist<<<E_TOT / 256, 256, 0, stream>>>(dstA, cnt);
    k_scan<<<1, 1024, 0, stream>>>(cnt, rowptr, cursor);
    k_scatter<<<E_TOT / 256, 256, 0, stream>>>(dstA, cursor, sortedPos);
    k_fold<<<(12 * 160 * 64 + 12 * 64 + 255) / 256, 256, 0, stream>>>(
        phi_e_W1, phi_e_b1, lig_ee_W, lig_ee_b, poc_ee_W, poc_ee_b, cross_ee_W, cross_ee_b,
        effW, beff);
    k_pack_g1<<<(12 * 1280 + 255) / 256, 256, 0, stream>>>(effW, Bg1);
    k_pack_g23<<<(4 * 1024 + 255) / 256, 256, 0, stream>>>(phi_e_W2, phi_x_W1, Bg23);
    k_pack_weights<<<(4 * 48 * 256) / 256, 256, 0, stream>>>(phi_h_W1, phi_h_W2, Wp);
    k_embed<<<(N_TOT * 64) / 256, 256, 0, stream>>>(
        lig_x, lig_h, poc_x, poc_h, t, lig_emb_W, lig_emb_b, poc_emb_W, poc_emb_b, h, xx);

    // ---- layers ----
    for (int l = 0; l < 4; ++l) {
        hipMemsetAsync(coord, 0, (size_t)N_TOT * 3 * 4, stream);
        k_edge_mfma<<<E_TOT / 64, 256, 0, stream>>>(
            h, xx, srcA, dstA, sortedPos, lig_attr, poc_attr, cross_attr,
            Bg1 + (size_t)l * 3 * 5 * 4 * 512, beff + (size_t)l * 3 * 64,
            Bg23 + (size_t)l * 16 * 512,
            phi_e_b2 + l * 64, phi_x_b1 + l * 64,
            phi_x_W2 + l * 64, phi_x_b2 + l,
            mBuf, coord);
        k_node<<<N_TOT / 64, 256, 0, stream>>>(
            h, xx, mBuf, rowptr, coord,
            Wp + (size_t)l * 48 * 256, phi_h_b1 + l * 64,
            Wp + (size_t)l * 48 * 256 + 32 * 256, phi_h_b2 + l * 64);
    }

    k_out<<<(N_LIG * 64) / 256, 256, 0, stream>>>(
        h, xx, lig_x, out_W1, out_b1, out_W2, out_b2, (float*)d_out);
}

// Round 4
// 865.246 us; speedup vs baseline: 5.1666x; 1.1622x over previous
//
#include <hip/hip_runtime.h>

#define N_LIG 16384
#define M_POC 32768
#define N_TOT (N_LIG + M_POC)           // 49152
#define E_LIG 163840
#define E_POC 327680
#define E_CROSS (N_LIG * 8)             // 131072
#define E_TOT (E_LIG + E_POC + E_CROSS) // 622592
#define TE 16                           // edges/nodes per wave tile

typedef __bf16 bf16_t;
typedef bf16_t bf16x8 __attribute__((ext_vector_type(8)));
typedef bf16_t bf16x4 __attribute__((ext_vector_type(4)));
typedef bf16_t bf16x2 __attribute__((ext_vector_type(2)));
typedef float f32x4 __attribute__((ext_vector_type(4)));

// e_in row: [h_src(0..63) | h_dst(64..127) | dist(128) | zero(129..131) | attr(132..147) | zero(..159)]
#define S1 168   // bf16 stride; 336B rows, 16B-aligned, non-pow2 bank spread
#define S2 72    // m rows
// per-wave LDS: einA 16*168*2=5376 | mA 16*72*2=2304 | dfL 16*4*4=256  => 7936 B; 31744/block
#define WAVE_BYTES 7936

__device__ __forceinline__ float silu_f(float v) { return v / (1.0f + __expf(-v)); }

__device__ __forceinline__ float tanh_f(float v) {
    float a = fabsf(v);
    float t = __expf(-2.0f * a);
    float r = (1.0f - t) / (1.0f + t);
    return copysignf(r, v);
}

__device__ __forceinline__ void atomic_add_f32(float* p, float v) {
    __hip_atomic_fetch_add(p, v, __ATOMIC_RELAXED, __HIP_MEMORY_SCOPE_AGENT);
}

// ---------------- setup kernels ----------------

// builds src/dst arrays AND zeroes the histogram bins (hist runs in the next kernel)
__global__ void k_build_edges(const int* __restrict__ lig_ei, const int* __restrict__ poc_ei,
                              const int* __restrict__ cross_ei,
                              int* __restrict__ srcA, int* __restrict__ dstA,
                              int* __restrict__ cnt) {
    int e = blockIdx.x * blockDim.x + threadIdx.x;
    if (e < N_TOT) cnt[e] = 0;
    if (e >= E_TOT) return;
    int s, d;
    if (e < E_LIG) {
        s = lig_ei[e];
        d = lig_ei[E_LIG + e];
    } else if (e < E_LIG + E_POC) {
        int i = e - E_LIG;
        s = poc_ei[i] + N_LIG;
        d = poc_ei[E_POC + i] + N_LIG;
    } else {
        int i = e - E_LIG - E_POC;
        s = cross_ei[i] + N_LIG;
        d = cross_ei[E_CROSS + i];
    }
    srcA[e] = s;
    dstA[e] = d;
}

__global__ void k_hist(const int* __restrict__ dstA, int* __restrict__ cnt) {
    int e = blockIdx.x * blockDim.x + threadIdx.x;
    if (e < E_TOT) atomicAdd(&cnt[dstA[e]], 1);
}

// single block, 1024 threads, 48 bins per thread
__global__ __launch_bounds__(1024) void k_scan(const int* __restrict__ cnt,
                                               int* __restrict__ rowptr,
                                               int* __restrict__ cursor) {
    __shared__ int sums[1024];
    int tid = threadIdx.x;
    int local[48];
    int s = 0;
    for (int i = 0; i < 48; ++i) { local[i] = s; s += cnt[tid * 48 + i]; }
    sums[tid] = s;
    __syncthreads();
    for (int off = 1; off < 1024; off <<= 1) {
        int v = (tid >= off) ? sums[tid - off] : 0;
        __syncthreads();
        sums[tid] += v;
        __syncthreads();
    }
    int base = (tid == 0) ? 0 : sums[tid - 1];
    for (int i = 0; i < 48; ++i) {
        int v = base + local[i];
        int idx = tid * 48 + i;
        rowptr[idx] = v;
        cursor[idx] = v;
    }
    if (tid == 1023) rowptr[N_TOT] = sums[1023];
}

__global__ void k_scatter(const int* __restrict__ dstA, int* __restrict__ cursor,
                          int* __restrict__ sortedPos) {
    int e = blockIdx.x * blockDim.x + threadIdx.x;
    if (e < E_TOT) sortedPos[e] = atomicAdd(&cursor[dstA[e]], 1);
}

// ---- fused weight prep: Bg1 (edge GEMM1 frags, embedding folded), Bg23, node f32 pack, beff ----
#define PK_G1   (12 * 5 * 4 * 64)                     // 15360
#define PK_G23  (4 * 4 * 4 * 64)                      // 4096
#define PK_WP   (4 * 48 * 256)                        // 49152
#define PK_BEFF (12 * 64)                             // 768
#define PK_TOT  (PK_G1 + PK_G23 + PK_WP + PK_BEFF)    // 69376

__global__ void k_pack_all(const float* __restrict__ phi_e_W1, const float* __restrict__ phi_e_b1,
                           const float* __restrict__ lig_ee_W, const float* __restrict__ lig_ee_b,
                           const float* __restrict__ poc_ee_W, const float* __restrict__ poc_ee_b,
                           const float* __restrict__ cross_ee_W, const float* __restrict__ cross_ee_b,
                           const float* __restrict__ phi_e_W2, const float* __restrict__ phi_x_W1,
                           const float* __restrict__ phi_h_W1, const float* __restrict__ phi_h_W2,
                           bf16_t* __restrict__ Bg1, bf16_t* __restrict__ Bg23,
                           float* __restrict__ Wp, float* __restrict__ beff) {
    int tid = blockIdx.x * blockDim.x + threadIdx.x;
    if (tid < PK_G1) {
        // Bg1[((lt*5+c)*4+nt)*512 + lane*8 + j]: effW computed on the fly (embedding folded)
        int lt = tid / 1280;
        int rem = tid - lt * 1280;
        int c = rem >> 8;
        int nt = (rem >> 6) & 3;
        int lane = rem & 63;
        int l = lt / 3, t = lt % 3;
        const float* W1l = phi_e_W1 + l * 193 * 64;
        const float* We; int K;
        if (t == 0) { We = lig_ee_W; K = 6; }
        else if (t == 1) { We = poc_ee_W; K = 16; }
        else { We = cross_ee_W; K = 16; }
        int col = nt * 16 + (lane & 15);
        int k0 = c * 32 + (lane >> 4) * 8;
        #pragma unroll
        for (int j = 0; j < 8; ++j) {
            int row = k0 + j;
            float v = 0.0f;
            if (row < 129) v = W1l[row * 64 + col];
            else if (row >= 132 && row < 132 + K) {
                int kk = row - 132;
                float a = 0.0f;
                for (int q = 0; q < 64; ++q) a = fmaf(We[kk * 64 + q], W1l[(129 + q) * 64 + col], a);
                v = a;
            }
            Bg1[(size_t)tid * 8 + j] = (bf16_t)v;
        }
    } else if (tid < PK_G1 + PK_G23) {
        int u = tid - PK_G1;
        int lane = u & 63;
        int nt = (u >> 6) & 3;
        int c = (u >> 8) & 3;
        int l = u >> 10;
        const float* W = (c < 2) ? (phi_e_W2 + l * 4096) : (phi_x_W1 + l * 4096);
        int kb = (c & 1) * 32;
        int col = nt * 16 + (lane & 15);
        int k0 = kb + (lane >> 4) * 8;
        #pragma unroll
        for (int j = 0; j < 8; ++j)
            Bg23[(size_t)u * 8 + j] = (bf16_t)W[(k0 + j) * 64 + col];
    } else if (tid < PK_G1 + PK_G23 + PK_WP) {
        int idx = tid - PK_G1 - PK_G23;
        int l = idx / (48 * 256);
        int rem = idx - l * (48 * 256);
        int c = rem / 256;
        int q = rem - c * 256;
        int j = q >> 2;
        int kk = q & 3;
        const float* W; int Ksrc; int k4;
        if (c < 32) { W = phi_h_W1 + l * 128 * 64; Ksrc = 128; k4 = c; }
        else        { W = phi_h_W2 + l * 64 * 64;  Ksrc = 64;  k4 = c - 32; }
        int k = k4 * 4 + kk;
        Wp[idx] = (k < Ksrc) ? W[k * 64 + j] : 0.0f;
    } else if (tid < PK_TOT) {
        int u = tid - PK_G1 - PK_G23 - PK_WP;
        int j = u & 63;
        int lt = u >> 6;
        int l = lt / 3, t = lt % 3;
        const float* W1l = phi_e_W1 + l * 193 * 64;
        const float* Be = (t == 0) ? lig_ee_b : ((t == 1) ? poc_ee_b : cross_ee_b);
        float v = phi_e_b1[l * 64 + j];
        for (int q = 0; q < 64; ++q) v = fmaf(Be[q], W1l[(129 + q) * 64 + j], v);
        beff[u] = v;
    }
}

__global__ void k_embed(const float* __restrict__ lig_x, const float* __restrict__ lig_h,
                        const float* __restrict__ poc_x, const float* __restrict__ poc_h,
                        const float* __restrict__ t,
                        const float* __restrict__ ligW, const float* __restrict__ ligB,
                        const float* __restrict__ pocW, const float* __restrict__ pocB,
                        float* __restrict__ h, bf16_t* __restrict__ hB, float* __restrict__ x) {
    int gid = blockIdx.x * blockDim.x + threadIdx.x;
    int n = gid >> 6;
    int lane = gid & 63;
    if (n >= N_TOT) return;
    float a;
    if (n < N_LIG) {
        a = ligB[lane];
        #pragma unroll
        for (int k = 0; k < 17; ++k) a = fmaf(lig_h[n * 17 + k], ligW[k * 64 + lane], a);
        a = fmaf(t[0], ligW[17 * 64 + lane], a);
        if (lane < 3) x[n * 3 + lane] = lig_x[n * 3 + lane];
    } else {
        int p = n - N_LIG;
        a = pocB[lane];
        #pragma unroll
        for (int k = 0; k < 29; ++k) a = fmaf(poc_h[p * 29 + k], pocW[k * 64 + lane], a);
        if (lane < 3) x[n * 3 + lane] = poc_x[p * 3 + lane];
    }
    h[n * 64 + lane] = a;
    hB[n * 64 + lane] = (bf16_t)a;
}

// ---------------- per-layer MFMA edge kernel ----------------
// Block = 256 (4 waves); wave = 16 edges (original order; tile type-uniform).
// h staged from bf16 shadow (no cvt); m stored to mBuf via LDS row re-read (coalesced 16B).
__global__ __launch_bounds__(256) void k_edge_mfma(
    const bf16_t* __restrict__ hB, const float* __restrict__ x,
    const int* __restrict__ srcA, const int* __restrict__ dstA,
    const int* __restrict__ sortedPos,
    const float* __restrict__ lig_attr, const float* __restrict__ poc_attr,
    const float* __restrict__ cross_attr,
    const bf16_t* __restrict__ Bg1L,   // + t*5*4*512 inside
    const float* __restrict__ beffL,   // + t*64 inside
    const bf16_t* __restrict__ Bg23L,
    const float* __restrict__ b2, const float* __restrict__ bx1,
    const float* __restrict__ Wx2, const float* __restrict__ bx2,
    bf16_t* __restrict__ mBuf, float* __restrict__ coord_agg) {
    __shared__ __align__(16) char lds[4 * WAVE_BYTES];
    const int lane = threadIdx.x & 63;
    const int wave = threadIdx.x >> 6;
    bf16_t* einA = (bf16_t*)(lds + wave * WAVE_BYTES);
    bf16_t* mA   = (bf16_t*)(lds + wave * WAVE_BYTES + 5376);
    float*  dfL  = (float*)(lds + wave * WAVE_BYTES + 5376 + 2304);
    const int base = (blockIdx.x * 4 + wave) * TE;

    // edge type (tile-uniform)
    int t; const float* attrBase;
    if (base < E_LIG) { t = 0; attrBase = lig_attr + (size_t)base * 6; }
    else if (base < E_LIG + E_POC) { t = 1; attrBase = poc_attr + (size_t)(base - E_LIG) * 16; }
    else { t = 2; attrBase = cross_attr + (size_t)(base - E_LIG - E_POC) * 16; }

    // per-lane edge metadata for edge (lane&15)
    const int e16 = base + (lane & 15);
    const int sv = srcA[e16];
    const int dv = dstA[e16];
    const int sp = sortedPos[e16];

    // ---- zero cols 128..159 of all rows (1 instr) ----
    {
        bf16x8 z = {(bf16_t)0.f, (bf16_t)0.f, (bf16_t)0.f, (bf16_t)0.f,
                    (bf16_t)0.f, (bf16_t)0.f, (bf16_t)0.f, (bf16_t)0.f};
        *(bf16x8*)(einA + (lane >> 2) * S1 + 128 + (lane & 3) * 8) = z;
    }

    // ---- h_src / h_dst gathers: bf16x4 per lane, 4 rows per instruction, no cvt ----
    #pragma unroll
    for (int i = 0; i < 4; ++i) {
        const int row = i * 4 + (lane >> 4);
        const int s = __shfl(sv, row, 64);
        const int d = __shfl(dv, row, 64);
        bf16x4 hs = *(const bf16x4*)(hB + (size_t)s * 64 + (lane & 15) * 4);
        bf16x4 hd = *(const bf16x4*)(hB + (size_t)d * 64 + (lane & 15) * 4);
        *(bf16x4*)(einA + row * S1 + (lane & 15) * 4) = hs;
        *(bf16x4*)(einA + row * S1 + 64 + (lane & 15) * 4) = hd;
    }

    // ---- x / dist: lane r<16 handles edge r ----
    if (lane < 16) {
        const float* xs = x + (size_t)sv * 3;
        const float* xd = x + (size_t)dv * 3;
        float d0 = xs[0] - xd[0];
        float d1 = xs[1] - xd[1];
        float d2 = xs[2] - xd[2];
        float dist = (d0 * d0 + d1 * d1 + d2 * d2) * 0.01f;
        einA[lane * S1 + 128] = (bf16_t)dist;
        *(float4*)(dfL + lane * 4) = (float4){d0, d1, d2, dist};
    }

    // ---- attr tile: cols 132.. (raw attrs; Wee folded into W1eff) ----
    {
        const int r = lane >> 2, q = lane & 3;
        if (t == 0) {
            if (q < 3) {
                float2 a = *(const float2*)(attrBase + r * 6 + q * 2);
                bf16x2 av = {(bf16_t)a.x, (bf16_t)a.y};
                *(bf16x2*)(einA + r * S1 + 132 + q * 2) = av;
            }
        } else {
            float4 a = *(const float4*)(attrBase + r * 16 + q * 4);
            bf16x4 av = {(bf16_t)a.x, (bf16_t)a.y, (bf16_t)a.z, (bf16_t)a.w};
            *(bf16x4*)(einA + r * S1 + 132 + q * 4) = av;
        }
    }
    __syncthreads();

    const int mcol = lane & 15;
    const int mrow0 = (lane >> 4) * 4;
    const int kgrp = lane >> 4;

    // ---- GEMM1: m1 = silu(e_in @ W1eff + beff) : 5 k-chunks x 4 n-tiles ----
    const bf16_t* Bg1 = Bg1L + (size_t)t * 5 * 4 * 512;
    const float* beff = beffL + t * 64;
    f32x4 acc1[4];
    #pragma unroll
    for (int nt = 0; nt < 4; ++nt) {
        float bv = beff[nt * 16 + mcol];
        acc1[nt] = (f32x4){bv, bv, bv, bv};
    }
    const bf16_t* aBase = einA + mcol * S1 + kgrp * 8;
    #pragma unroll
    for (int c = 0; c < 5; ++c) {
        bf16x8 af = *(const bf16x8*)(aBase + c * 32);
        #pragma unroll
        for (int nt = 0; nt < 4; ++nt) {
            bf16x8 bfr = *(const bf16x8*)(Bg1 + ((size_t)(c * 4 + nt) * 64 + lane) * 8);
            acc1[nt] = __builtin_amdgcn_mfma_f32_16x16x32_bf16(af, bfr, acc1[nt], 0, 0, 0);
        }
    }
    __syncthreads();
    #pragma unroll
    for (int nt = 0; nt < 4; ++nt)
        #pragma unroll
        for (int g = 0; g < 4; ++g)
            mA[(mrow0 + g) * S2 + nt * 16 + mcol] = (bf16_t)silu_f(acc1[nt][g]);
    __syncthreads();

    // ---- GEMM2: m = silu(m1 @ W2 + b2) ----
    f32x4 acc2[4];
    #pragma unroll
    for (int nt = 0; nt < 4; ++nt) {
        float bv = b2[nt * 16 + mcol];
        acc2[nt] = (f32x4){bv, bv, bv, bv};
    }
    const bf16_t* aBase2 = mA + mcol * S2 + kgrp * 8;
    #pragma unroll
    for (int c = 0; c < 2; ++c) {
        bf16x8 af = *(const bf16x8*)(aBase2 + c * 32);
        #pragma unroll
        for (int nt = 0; nt < 4; ++nt) {
            bf16x8 bfr = *(const bf16x8*)(Bg23L + ((size_t)(c * 4 + nt) * 64 + lane) * 8);
            acc2[nt] = __builtin_amdgcn_mfma_f32_16x16x32_bf16(af, bfr, acc2[nt], 0, 0, 0);
        }
    }
    __syncthreads();   // mA (m1) fully consumed by all lanes before overwrite
    #pragma unroll
    for (int nt = 0; nt < 4; ++nt)
        #pragma unroll
        for (int g = 0; g < 4; ++g)
            mA[(mrow0 + g) * S2 + nt * 16 + mcol] = (bf16_t)silu_f(acc2[nt][g]);
    __syncthreads();

    // ---- store m rows to mBuf via LDS re-read: 2 coalesced 16B stores/lane ----
    #pragma unroll
    for (int p = 0; p < 2; ++p) {
        const int r = p * 8 + (lane >> 3);
        const int c8 = (lane & 7) * 8;
        bf16x8 mrow = *(const bf16x8*)(mA + r * S2 + c8);
        const int pos = __shfl(sp, r, 64);
        *(bf16x8*)(mBuf + (size_t)pos * 64 + c8) = mrow;
    }

    // ---- GEMM3: p = silu(m @ Wx1 + bx1) ----
    f32x4 acc3[4];
    #pragma unroll
    for (int nt = 0; nt < 4; ++nt) {
        float bv = bx1[nt * 16 + mcol];
        acc3[nt] = (f32x4){bv, bv, bv, bv};
    }
    const bf16_t* Bg3 = Bg23L + (size_t)2 * 4 * 512;
    #pragma unroll
    for (int c = 0; c < 2; ++c) {
        bf16x8 af = *(const bf16x8*)(aBase2 + c * 32);
        #pragma unroll
        for (int nt = 0; nt < 4; ++nt) {
            bf16x8 bfr = *(const bf16x8*)(Bg3 + ((size_t)(c * 4 + nt) * 64 + lane) * 8);
            acc3[nt] = __builtin_amdgcn_mfma_f32_16x16x32_bf16(af, bfr, acc3[nt], 0, 0, 0);
        }
    }

    // ---- cw = tanh(silu(p) . Wx2 + bx2); coord atomics (ligand dst only, 3 lanes/edge) ----
    const float bx2v = bx2[0];
    float s[4] = {0.f, 0.f, 0.f, 0.f};
    #pragma unroll
    for (int nt = 0; nt < 4; ++nt) {
        float w = Wx2[nt * 16 + mcol];
        #pragma unroll
        for (int g = 0; g < 4; ++g) s[g] = fmaf(silu_f(acc3[nt][g]), w, s[g]);
    }
    #pragma unroll
    for (int g = 0; g < 4; ++g) {
        float p = s[g];
        #pragma unroll
        for (int off = 1; off < 16; off <<= 1) p += __shfl_xor(p, off, 64);
        const float cw = tanh_f(p + bx2v);
        const int d = __shfl(dv, mrow0 + g, 64);
        if (d < N_LIG && mcol < 3)
            atomic_add_f32(&coord_agg[d * 3 + mcol], dfL[(mrow0 + g) * 4 + mcol] * cw);
    }
}

// ---------------- per-layer node update: vectorized mBuf gather + f32 MLP ----------------
__global__ __launch_bounds__(256) void k_node(
    float* __restrict__ h, bf16_t* __restrict__ hB, float* __restrict__ x,
    const bf16_t* __restrict__ mBuf, const int* __restrict__ rowptr,
    float* __restrict__ coord,
    const float* __restrict__ Wh1p, const float* __restrict__ bh1,
    const float* __restrict__ Wh2p, const float* __restrict__ bh2) {
    __shared__ __align__(16) float lds[4][TE * 128];
    const int lane = threadIdx.x & 63;
    const int wave = threadIdx.x >> 6;
    float* inL = lds[wave];
    const int base = (blockIdx.x * 4 + wave) * TE;

    // h staging: contiguous, 4x float4 per lane
    #pragma unroll
    for (int i = 0; i < 4; ++i) {
        int fidx = i * 256 + lane * 4;
        float4 v = *(const float4*)(h + (size_t)base * 64 + fidx);
        *(float4*)(inL + (fidx >> 6) * 128 + (fidx & 63)) = v;
    }

    // msg gather: 4 sub-groups x 16 feature-quads; 4 edges per wave-iteration
    const int n16 = base + (lane & 15);
    const int rp0 = rowptr[n16];
    const int rp1 = rowptr[n16 + 1];
    const int sub = lane >> 4;          // 0..3
    const int f4 = (lane & 15) * 4;     // feature base
    for (int r = 0; r < TE; ++r) {
        const int s0 = __shfl(rp0, r, 64);
        const int s1 = __shfl(rp1, r, 64);
        float a0 = 0.f, a1 = 0.f, a2 = 0.f, a3 = 0.f;
        for (int i = s0 + sub; i < s1; i += 4) {
            bf16x4 v = *(const bf16x4*)(mBuf + (size_t)i * 64 + f4);
            a0 += (float)v[0]; a1 += (float)v[1]; a2 += (float)v[2]; a3 += (float)v[3];
        }
        a0 += __shfl_xor(a0, 16, 64); a1 += __shfl_xor(a1, 16, 64);
        a2 += __shfl_xor(a2, 16, 64); a3 += __shfl_xor(a3, 16, 64);
        a0 += __shfl_xor(a0, 32, 64); a1 += __shfl_xor(a1, 32, 64);
        a2 += __shfl_xor(a2, 32, 64); a3 += __shfl_xor(a3, 32, 64);
        if (lane < 16)
            *(float4*)(inL + r * 128 + 64 + f4) = (float4){a0, a1, a2, a3};
    }
    __syncthreads();

    float acc[TE];
    #pragma unroll
    for (int r = 0; r < TE; ++r) acc[r] = bh1[lane];
    for (int c = 0; c < 32; ++c) {
        const float4 w = *(const float4*)(Wh1p + (c * 64 + lane) * 4);
        #pragma unroll
        for (int r = 0; r < TE; ++r) {
            const float4 v = *(const float4*)(inL + r * 128 + c * 4);
            acc[r] = fmaf(v.x, w.x, fmaf(v.y, w.y, fmaf(v.z, w.z, fmaf(v.w, w.w, acc[r]))));
        }
    }
    __syncthreads();
    #pragma unroll
    for (int r = 0; r < TE; ++r) inL[r * 64 + lane] = silu_f(acc[r]);
    __syncthreads();

    float acc2[TE];
    #pragma unroll
    for (int r = 0; r < TE; ++r) acc2[r] = bh2[lane];
    for (int c = 0; c < 16; ++c) {
        const float4 w = *(const float4*)(Wh2p + (c * 64 + lane) * 4);
        #pragma unroll
        for (int r = 0; r < TE; ++r) {
            const float4 v = *(const float4*)(inL + r * 64 + c * 4);
            acc2[r] = fmaf(v.x, w.x, fmaf(v.y, w.y, fmaf(v.z, w.z, fmaf(v.w, w.w, acc2[r]))));
        }
    }
    for (int r = 0; r < TE; ++r) {
        const int n = base + r;
        float hv = h[n * 64 + lane] + acc2[r];
        h[n * 64 + lane] = hv;
        hB[n * 64 + lane] = (bf16_t)hv;
        if (lane < 3) {
            if (n < N_LIG) x[n * 3 + lane] += coord[n * 3 + lane];
            coord[n * 3 + lane] = 0.0f;   // self-clear for next layer (replaces memset)
        }
    }
}

// ---------------- output head ----------------
__global__ void k_out(const float* __restrict__ h, const float* __restrict__ x,
                      const float* __restrict__ lig_x,
                      const float* __restrict__ oW1, const float* __restrict__ ob1,
                      const float* __restrict__ oW2, const float* __restrict__ ob2,
                      float* __restrict__ out) {
    int gid = blockIdx.x * blockDim.x + threadIdx.x;
    int n = gid >> 6;
    int lane = gid & 63;
    if (n >= N_LIG) return;
    float hv = h[n * 64 + lane];
    float a = ob1[lane];
    #pragma unroll
    for (int k = 0; k < 64; ++k) a = fmaf(__shfl(hv, k, 64), oW1[k * 64 + lane], a);
    float p = silu_f(a) * oW2[lane];
    #pragma unroll
    for (int off = 32; off > 0; off >>= 1) p += __shfl_xor(p, off, 64);
    float scale = p + ob2[0];
    if (lane < 3) out[n * 3 + lane] = scale * (x[n * 3 + lane] - lig_x[n * 3 + lane]);
}

// ---------------- launch ----------------
extern "C" void kernel_launch(void* const* d_in, const int* in_sizes, int n_in,
                              void* d_out, int out_size, void* d_ws, size_t ws_size,
                              hipStream_t stream) {
    const float* lig_x      = (const float*)d_in[0];
    const float* lig_h      = (const float*)d_in[1];
    const float* poc_x      = (const float*)d_in[2];
    const float* poc_h      = (const float*)d_in[3];
    const int*   lig_ei     = (const int*)d_in[4];
    const float* lig_attr   = (const float*)d_in[5];
    const int*   poc_ei     = (const int*)d_in[6];
    const float* poc_attr   = (const float*)d_in[7];
    const int*   cross_ei   = (const int*)d_in[8];
    const float* cross_attr = (const float*)d_in[9];
    const float* t          = (const float*)d_in[10];
    const float* lig_emb_W  = (const float*)d_in[11];
    const float* lig_emb_b  = (const float*)d_in[12];
    const float* poc_emb_W  = (const float*)d_in[13];
    const float* poc_emb_b  = (const float*)d_in[14];
    const float* lig_ee_W   = (const float*)d_in[15];
    const float* lig_ee_b   = (const float*)d_in[16];
    const float* poc_ee_W   = (const float*)d_in[17];
    const float* poc_ee_b   = (const float*)d_in[18];
    const float* cross_ee_W = (const float*)d_in[19];
    const float* cross_ee_b = (const float*)d_in[20];
    const float* phi_e_W1   = (const float*)d_in[21];
    const float* phi_e_b1   = (const float*)d_in[22];
    const float* phi_e_W2   = (const float*)d_in[23];
    const float* phi_e_b2   = (const float*)d_in[24];
    const float* phi_x_W1   = (const float*)d_in[25];
    const float* phi_x_b1   = (const float*)d_in[26];
    const float* phi_x_W2   = (const float*)d_in[27];
    const float* phi_x_b2   = (const float*)d_in[28];
    const float* phi_h_W1   = (const float*)d_in[29];
    const float* phi_h_b1   = (const float*)d_in[30];
    const float* phi_h_W2   = (const float*)d_in[31];
    const float* phi_h_b2   = (const float*)d_in[32];
    const float* out_W1     = (const float*)d_in[33];
    const float* out_b1     = (const float*)d_in[34];
    const float* out_W2     = (const float*)d_in[35];
    const float* out_b2     = (const float*)d_in[36];

    // ---- workspace carve (256B aligned chunks) ----
    char* p = (char*)d_ws;
    auto carve = [&](size_t bytes) { char* r = p; p += (bytes + 255) & ~(size_t)255; return r; };
    float*  h      = (float*)carve((size_t)N_TOT * 64 * 4);
    bf16_t* hB     = (bf16_t*)carve((size_t)N_TOT * 64 * 2);
    float*  xx     = (float*)carve((size_t)N_TOT * 3 * 4);
    float*  coord  = (float*)carve((size_t)N_TOT * 3 * 4);
    float*  Wp     = (float*)carve((size_t)4 * 48 * 256 * 4);
    float*  beff   = (float*)carve((size_t)12 * 64 * 4);
    bf16_t* Bg1    = (bf16_t*)carve((size_t)12 * 5 * 4 * 512 * 2);
    bf16_t* Bg23   = (bf16_t*)carve((size_t)4 * 16 * 512 * 2);
    int*    srcA   = (int*)carve((size_t)E_TOT * 4);
    int*    dstA   = (int*)carve((size_t)E_TOT * 4);
    int*    sortedPos = (int*)carve((size_t)E_TOT * 4);
    int*    cnt    = (int*)carve((size_t)N_TOT * 4);
    int*    cursor = (int*)carve((size_t)N_TOT * 4);
    int*    rowptr = (int*)carve((size_t)(N_TOT + 1) * 4);
    bf16_t* mBuf   = (bf16_t*)carve((size_t)E_TOT * 64 * 2);

    // ---- setup (once per launch) ----
    k_build_edges<<<E_TOT / 256, 256, 0, stream>>>(lig_ei, poc_ei, cross_ei, srcA, dstA, cnt);
    k_hist<<<E_TOT / 256, 256, 0, stream>>>(dstA, cnt);
    k_scan<<<1, 1024, 0, stream>>>(cnt, rowptr, cursor);
    k_scatter<<<E_TOT / 256, 256, 0, stream>>>(dstA, cursor, sortedPos);
    k_pack_all<<<(PK_TOT + 255) / 256, 256, 0, stream>>>(
        phi_e_W1, phi_e_b1, lig_ee_W, lig_ee_b, poc_ee_W, poc_ee_b, cross_ee_W, cross_ee_b,
        phi_e_W2, phi_x_W1, phi_h_W1, phi_h_W2, Bg1, Bg23, Wp, beff);
    k_embed<<<(N_TOT * 64) / 256, 256, 0, stream>>>(
        lig_x, lig_h, poc_x, poc_h, t, lig_emb_W, lig_emb_b, poc_emb_W, poc_emb_b, h, hB, xx);
    hipMemsetAsync(coord, 0, (size_t)N_TOT * 3 * 4, stream);  // layer 0 only; k_node self-clears after

    // ---- layers ----
    for (int l = 0; l < 4; ++l) {
        k_edge_mfma<<<E_TOT / 64, 256, 0, stream>>>(
            hB, xx, srcA, dstA, sortedPos, lig_attr, poc_attr, cross_attr,
            Bg1 + (size_t)l * 3 * 5 * 4 * 512, beff + (size_t)l * 3 * 64,
            Bg23 + (size_t)l * 16 * 512,
            phi_e_b2 + l * 64, phi_x_b1 + l * 64,
            phi_x_W2 + l * 64, phi_x_b2 + l,
            mBuf, coord);
        k_node<<<N_TOT / 64, 256, 0, stream>>>(
            h, hB, xx, mBuf, rowptr, coord,
            Wp + (size_t)l * 48 * 256, phi_h_b1 + l * 64,
            Wp + (size_t)l * 48 * 256 + 32 * 256, phi_h_b2 + l * 64);
    }

    k_out<<<(N_LIG * 64) / 256, 256, 0, stream>>>(
        h, xx, lig_x, out_W1, out_b1, out_W2, out_b2, (float*)d_out);
}